// Round 8
// baseline (1662.735 us; speedup 1.0000x reference)
//
#include <hip/hip_runtime.h>
#include <cstdint>
#include <cstddef>

#define B_DIM   4096
#define IN_DIM  2048
#define OUT_DIM 4096

typedef __attribute__((ext_vector_type(8))) __bf16 bf16x8;
typedef __attribute__((ext_vector_type(4))) float  f32x4;
typedef unsigned short ushortT;

__device__ __forceinline__ ushortT f2bf(float f) {
    unsigned int u = __float_as_uint(f);
    u += 0x7FFFu + ((u >> 16) & 1u);          // round-to-nearest-even
    return (ushortT)(u >> 16);
}
__device__ __forceinline__ float bf2f(ushortT b) {
    return __uint_as_float(((unsigned int)b) << 16);
}

// global -> LDS direct DMA, 16 B per lane (wave-uniform LDS base, lane i at +i*16).
__device__ __forceinline__ void gload16(const void* g, void* l) {
    __builtin_amdgcn_global_load_lds(
        (const __attribute__((address_space(1))) void*)g,
        (__attribute__((address_space(3))) void*)l, 16, 0, 0);
}

// G0 = bf16(-0.05 * sqrt(in^2 + 1e-6))   (step-0 gradient: x=0 -> exp(-u)=1)
__global__ void prep_g0_kernel(const float* __restrict__ in, ushortT* __restrict__ Gb) {
    int i = blockIdx.x * 256 + threadIdx.x;
    float4 v = reinterpret_cast<const float4*>(in)[i];
    ushort4 g;
    g.x = f2bf(-0.05f * sqrtf(v.x * v.x + 1e-6f));
    g.y = f2bf(-0.05f * sqrtf(v.y * v.y + 1e-6f));
    g.z = f2bf(-0.05f * sqrtf(v.z * v.z + 1e-6f));
    g.w = f2bf(-0.05f * sqrtf(v.w * v.w + 1e-6f));
    reinterpret_cast<ushort4*>(Gb)[i] = g;
}

// Wb = bf16(W) [OUT][IN];  WTb = bf16(W^T) [IN][OUT]
__global__ void conv_w_kernel(const float* __restrict__ W, ushortT* __restrict__ Wb,
                              ushortT* __restrict__ WTb) {
    __shared__ float tile[64][65];
    const int i0 = blockIdx.x * 64;
    const int j0 = blockIdx.y * 64;
    const int c  = threadIdx.x & 63;
    const int rq = threadIdx.x >> 6;
#pragma unroll
    for (int rp = 0; rp < 16; ++rp) {
        int row = rp * 4 + rq;
        float w = W[(size_t)(j0 + row) * IN_DIM + i0 + c];
        tile[row][c] = w;
        Wb[(size_t)(j0 + row) * IN_DIM + i0 + c] = f2bf(w);
    }
    __syncthreads();
#pragma unroll
    for (int rp = 0; rp < 16; ++rp) {
        int row = rp * 4 + rq;
        WTb[(size_t)(i0 + row) * OUT_DIM + j0 + c] = f2bf(tile[c][row]);
    }
}

// ============================================================================
// Multi-block NT GEMM: C[M,N] = A[M,K]*Bm[N,K]^T, bf16 in / fp32 acc.
// Sized for >=2 resident blocks/CU so cross-block TLP fills barrier stalls and
// overlaps one block's epilogue with another's K-loop:
//   grad: BM=256,BN=128,NT=512 (8 waves 4Mx2N), ring-3 LDS = 72KB -> 2 blk/CU
//   fwd : BM=128,BN=128,NT=256 (4 waves 2Mx2N), ring-3 LDS = 48KB -> 3 blk/CU
// Per-wave output 64x64 (MR=NR=4). Per K-tile (BK=32), 1 barrier:
//   {vmcnt(L) [0 at tail]; s_barrier; sched_barrier; 8 ds_reads;
//    stage(tt+2); setprio(1); 16 MFMA; setprio(0)}
// Plain-C++ LDS reads: compiler inserts fine-grained lgkmcnt before MFMA use.
// Hazards (ring-3, stage-2-ahead, wave-uniform load counts):
//   RAW -- vmcnt(L)+barrier forces slot tt complete (slot tt+1 in flight).
//   WAR -- stage(tt+2) -> slot (tt-1)%3 issues after pub(tt+1) barrier, which
//          follows every wave's slot-(tt-1) reads (consumed 2 iters earlier).
// LDS XOR-swizzle slot^=(row>>1)&3 on 16B slots (both-sides, rule #21).
// Epilogue staged via LDS -> coalesced. State bf16-only (xb/acc1/acc2).
// ============================================================================
template <int EPI, int BM, int BN, int NT, int WMS>
__global__ __launch_bounds__(NT, 4)
void gemm_mb(const ushortT* __restrict__ A, const ushortT* __restrict__ Bm,
             int N, int K,
             const float* __restrict__ inb, ushortT* __restrict__ Gb,
             float* __restrict__ out,
             ushortT* __restrict__ acc1, ushortT* __restrict__ acc2,
             ushortT* __restrict__ xb) {
    constexpr int WAVES = NT / 64;
    constexpr int WNS   = WAVES / WMS;       // waves along N
    constexpr int ASZ   = BM * 64;           // A K-slab bytes (BM x 32 bf16)
    constexpr int BSZ   = BN * 64;
    constexpr int SLOT  = ASZ + BSZ;
    constexpr int CA    = (4 * BM) / NT;     // A gload chunks per tile
    constexpr int CB    = (4 * BN) / NT;     // B gload chunks per tile
    constexpr int L     = CA + CB;
    __shared__ alignas(16) char smem[3 * SLOT];

    const int tid  = threadIdx.x;
    const int lane = tid & 63;
    const int w    = tid >> 6;
    const int wm   = w / WNS;
    const int wn   = w % WNS;
    const int nbx  = N / BN;
    const int nwg  = gridDim.x;              // 512 everywhere (multiple of 8)
    const int cpx  = nwg >> 3;
    const int bid  = (int)blockIdx.x;
    const int swz  = (bid & 7) * cpx + (bid >> 3);   // XCD-aware bijective
    const int bx   = swz % nbx;
    const int by   = swz / nbx;
    const int row0 = by * BM;
    const int col0 = bx * BN;

    const size_t strideK2 = (size_t)K * 2;

    // ---- staging pointers (A chunks then B chunks);
    //      inverse-swizzled global source, linear LDS dest ----
    const char* gp[L]; int lo[L];
#pragma unroll
    for (int c = 0; c < CA; ++c) {
        int Lp  = c * NT + tid;
        int row = Lp >> 2, sl = Lp & 3;
        int src = sl ^ ((row >> 1) & 3);
        gp[c] = (const char*)A + (size_t)(row0 + row) * strideK2 + src * 16;
        lo[c] = c * NT * 16 + w * 1024;
    }
#pragma unroll
    for (int c = 0; c < CB; ++c) {
        int Lp  = c * NT + tid;
        int row = Lp >> 2, sl = Lp & 3;
        int src = sl ^ ((row >> 1) & 3);
        gp[CA + c] = (const char*)Bm + (size_t)(col0 + row) * strideK2 + src * 16;
        lo[CA + c] = ASZ + c * NT * 16 + w * 1024;
    }
    auto stage = [&](int tt) {
        char* sb = smem + (tt % 3) * SLOT;
        const size_t kb = (size_t)tt * 64;
#pragma unroll
        for (int c = 0; c < L; ++c) gload16(gp[c] + kb, sb + lo[c]);
    };

    // ---- swizzled fragment-read offsets ----
    int aRd[4], bRd[4];
#pragma unroll
    for (int m = 0; m < 4; ++m) {
        int row = wm * 64 + m * 16 + (lane & 15);
        aRd[m] = row * 64 + (((lane >> 4) ^ ((row >> 1) & 3)) * 16);
    }
#pragma unroll
    for (int n = 0; n < 4; ++n) {
        int row = wn * 64 + n * 16 + (lane & 15);
        bRd[n] = ASZ + row * 64 + (((lane >> 4) ^ ((row >> 1) & 3)) * 16);
    }

    f32x4 acc[4][4] = {};
    const int nt = K >> 5;

    stage(0); stage(1);                      // prologue: 2 tiles in flight

    for (int tt = 0; tt < nt; ++tt) {
        if (tt < nt - 1) asm volatile("s_waitcnt vmcnt(%0)" :: "n"(L) : "memory");
        else             asm volatile("s_waitcnt vmcnt(0)"  ::: "memory");
        __builtin_amdgcn_s_barrier();        // pub(tt): slot tt visible to all
        __builtin_amdgcn_sched_barrier(0);   // no load may hoist above the pub

        const char* sb = smem + (tt % 3) * SLOT;
        bf16x8 aF[4], bF[4];
#pragma unroll
        for (int n = 0; n < 4; ++n) bF[n] = *reinterpret_cast<const bf16x8*>(sb + bRd[n]);
#pragma unroll
        for (int m = 0; m < 4; ++m) aF[m] = *reinterpret_cast<const bf16x8*>(sb + aRd[m]);
        if (tt + 2 < nt) stage(tt + 2);      // gload issue hides under ds latency
        __builtin_amdgcn_s_setprio(1);
#pragma unroll
        for (int m = 0; m < 4; ++m)
#pragma unroll
            for (int n = 0; n < 4; ++n)
                acc[m][n] = __builtin_amdgcn_mfma_f32_16x16x32_bf16(aF[m], bF[n], acc[m][n], 0, 0, 0);
        __builtin_amdgcn_s_setprio(0);
    }

    __builtin_amdgcn_s_barrier();            // all reads retired; reuse LDS

    // ---- epilogue: per-wave LDS re-layout -> coalesced I/O ----
    // MFMA C layout (m89): acc[m][n][i] -> row (lane>>4)*4+i, col n*16+(lane&15)
    float* lep = (float*)(smem + w * 4352);  // [16][68] f32 per wave
    const int li = lane >> 4;
    const int lc = lane & 15;
    const int row0w = row0 + wm * 64;
    const int col0w = col0 + wn * 64;
#pragma unroll
    for (int m = 0; m < 4; ++m) {
#pragma unroll
        for (int n = 0; n < 4; ++n)
#pragma unroll
            for (int i = 0; i < 4; ++i)
                lep[(li * 4 + i) * 68 + n * 16 + lc] = acc[m][n][i];
        asm volatile("s_waitcnt lgkmcnt(0)" ::: "memory");
        __builtin_amdgcn_sched_barrier(0);
#pragma unroll
        for (int rr = 0; rr < 4; ++rr) {
            const int row = rr + li * 4;
            float4 v = *reinterpret_cast<const float4*>(&lep[row * 68 + lc * 4]);
            const size_t idx  = (size_t)(row0w + m * 16 + row) * N + col0w + lc * 4;
            const size_t idx4 = idx >> 2;
            if constexpr (EPI == 0) {
                float4 iv = reinterpret_cast<const float4*>(inb)[idx4];
                ushort4 g;
                g.x = f2bf(-0.05f * sqrtf(iv.x * iv.x + 1e-6f) * expf(-v.x));
                g.y = f2bf(-0.05f * sqrtf(iv.y * iv.y + 1e-6f) * expf(-v.y));
                g.z = f2bf(-0.05f * sqrtf(iv.z * iv.z + 1e-6f) * expf(-v.z));
                g.w = f2bf(-0.05f * sqrtf(iv.w * iv.w + 1e-6f) * expf(-v.w));
                *reinterpret_cast<ushort4*>(&Gb[idx]) = g;
            } else if constexpr (EPI == 1) {
                float4 iv = reinterpret_cast<const float4*>(inb)[idx4];
                float4 o;
                o.x = 0.05f * (1.0f + expf(-v.x)) * sqrtf(iv.x * iv.x + 1e-6f);
                o.y = 0.05f * (1.0f + expf(-v.y)) * sqrtf(iv.y * iv.y + 1e-6f);
                o.z = 0.05f * (1.0f + expf(-v.z)) * sqrtf(iv.z * iv.z + 1e-6f);
                o.w = 0.05f * (1.0f + expf(-v.w)) * sqrtf(iv.w * iv.w + 1e-6f);
                reinterpret_cast<float4*>(out)[idx4] = o;
            } else {
                ushort4 xu  = *reinterpret_cast<const ushort4*>(&xb[idx]);
                ushort4 a1u = *reinterpret_cast<const ushort4*>(&acc1[idx]);
                ushort4 a2u = *reinterpret_cast<const ushort4*>(&acc2[idx]);
                float xs[4] = {bf2f(xu.x), bf2f(xu.y), bf2f(xu.z), bf2f(xu.w)};
                float vs[4] = {v.x, v.y, v.z, v.w};
                ushortT a1s[4] = {a1u.x, a1u.y, a1u.z, a1u.w};
                ushortT a2s[4] = {a2u.x, a2u.y, a2u.z, a2u.w};
                ushortT a1n[4], a2n[4], xbn[4];
#pragma unroll
                for (int j = 0; j < 4; ++j) {
                    float g    = vs[j] + 0.02f * xs[j] + 0.1f * xs[j] * rsqrtf(xs[j] * xs[j] + 1e-6f);
                    float a1   = 0.9f * bf2f(a1s[j]) + 0.1f * g * g;
                    float inv  = rsqrtf(a1 + 1e-8f);
                    float r_   = 0.009f * g * inv;
                    float a2   = 0.9f * bf2f(a2s[j]) - r_;
                    float cand = xs[j] - r_;
                    float t_   = 0.0009f * inv;
                    float xn   = fmaxf(cand - t_, 0.0f) + fminf(cand + t_, 0.0f) + 0.9f * a2;
                    a1n[j] = f2bf(a1); a2n[j] = f2bf(a2); xbn[j] = f2bf(xn);
                }
                *reinterpret_cast<ushort4*>(&acc1[idx]) = make_ushort4(a1n[0], a1n[1], a1n[2], a1n[3]);
                *reinterpret_cast<ushort4*>(&acc2[idx]) = make_ushort4(a2n[0], a2n[1], a2n[2], a2n[3]);
                *reinterpret_cast<ushort4*>(&xb[idx])   = make_ushort4(xbn[0], xbn[1], xbn[2], xbn[3]);
            }
        }
        asm volatile("s_waitcnt lgkmcnt(0)" ::: "memory");   // lep reads done before next m
    }
}

extern "C" void kernel_launch(void* const* d_in, const int* in_sizes, int n_in,
                              void* d_out, int out_size, void* d_ws, size_t ws_size,
                              hipStream_t stream) {
    const float* in = (const float*)d_in[0];
    const float* W  = (const float*)d_in[1];
    float* out = (float*)d_out;
    char* ws = (char*)d_ws;

    // workspace layout — 144 MB total (state first for one contiguous memset)
    ushortT* acc1 = (ushortT*)(ws);                            // 32 MB bf16 [4096,4096]
    ushortT* acc2 = (ushortT*)(ws + ((size_t)32  << 20));      // 32 MB bf16
    ushortT* xb   = (ushortT*)(ws + ((size_t)64  << 20));      // 32 MB bf16
    ushortT* Wb   = (ushortT*)(ws + ((size_t)96  << 20));      // 16 MB bf16 [4096,2048]
    ushortT* WTb  = (ushortT*)(ws + ((size_t)112 << 20));      // 16 MB bf16 [2048,4096]
    ushortT* Gb   = (ushortT*)(ws + ((size_t)128 << 20));      // 16 MB bf16 [4096,2048]

    hipMemsetAsync(ws, 0, (size_t)96 << 20, stream);           // acc1, acc2, xb = 0

    prep_g0_kernel<<<dim3(B_DIM * IN_DIM / 4 / 256), dim3(256), 0, stream>>>(in, Gb);
    conv_w_kernel<<<dim3(IN_DIM / 64, OUT_DIM / 64), dim3(256), 0, stream>>>(W, Wb, WTb);

    // fwd/final: BM=128,BN=128 -> 32x16 = 512 blocks (3 blk/CU)
    // grad:      BM=256,BN=128 -> 16x32 = 512 blocks (2 blk/CU)
    for (int step = 0; step < 9; ++step) {
        if (step > 0) {
            gemm_mb<0, 128, 128, 256, 2><<<dim3(512), dim3(256), 0, stream>>>(
                xb, WTb, IN_DIM, OUT_DIM, in, Gb, nullptr, nullptr, nullptr, nullptr);
        }
        gemm_mb<2, 256, 128, 512, 4><<<dim3(512), dim3(512), 0, stream>>>(
            Gb, Wb, OUT_DIM, IN_DIM, nullptr, nullptr, nullptr, acc1, acc2, xb);
    }
    gemm_mb<1, 128, 128, 256, 2><<<dim3(512), dim3(256), 0, stream>>>(
        xb, WTb, IN_DIM, OUT_DIM, in, nullptr, out, nullptr, nullptr, nullptr);
}

// Round 9
// 1575.734 us; speedup vs baseline: 1.0552x; 1.0552x over previous
//
#include <hip/hip_runtime.h>
#include <cstdint>
#include <cstddef>

#define B_DIM   4096
#define IN_DIM  2048
#define OUT_DIM 4096

typedef __attribute__((ext_vector_type(8))) __bf16 bf16x8;
typedef __attribute__((ext_vector_type(4))) float  f32x4;
typedef unsigned short ushortT;

__device__ __forceinline__ ushortT f2bf(float f) {
    unsigned int u = __float_as_uint(f);
    u += 0x7FFFu + ((u >> 16) & 1u);          // round-to-nearest-even
    return (ushortT)(u >> 16);
}
__device__ __forceinline__ float bf2f(ushortT b) {
    return __uint_as_float(((unsigned int)b) << 16);
}

// global -> LDS direct DMA, 16 B per lane (wave-uniform LDS base, lane i at +i*16).
__device__ __forceinline__ void gload16(const void* g, void* l) {
    __builtin_amdgcn_global_load_lds(
        (const __attribute__((address_space(1))) void*)g,
        (__attribute__((address_space(3))) void*)l, 16, 0, 0);
}

// G0 = bf16(-0.05 * sqrt(in^2 + 1e-6))   (step-0 gradient: x=0 -> exp(-u)=1)
__global__ void prep_g0_kernel(const float* __restrict__ in, ushortT* __restrict__ Gb) {
    int i = blockIdx.x * 256 + threadIdx.x;
    float4 v = reinterpret_cast<const float4*>(in)[i];
    ushort4 g;
    g.x = f2bf(-0.05f * sqrtf(v.x * v.x + 1e-6f));
    g.y = f2bf(-0.05f * sqrtf(v.y * v.y + 1e-6f));
    g.z = f2bf(-0.05f * sqrtf(v.z * v.z + 1e-6f));
    g.w = f2bf(-0.05f * sqrtf(v.w * v.w + 1e-6f));
    reinterpret_cast<ushort4*>(Gb)[i] = g;
}

// Wb = bf16(W) [OUT][IN];  WTb = bf16(W^T) [IN][OUT]
__global__ void conv_w_kernel(const float* __restrict__ W, ushortT* __restrict__ Wb,
                              ushortT* __restrict__ WTb) {
    __shared__ float tile[64][65];
    const int i0 = blockIdx.x * 64;
    const int j0 = blockIdx.y * 64;
    const int c  = threadIdx.x & 63;
    const int rq = threadIdx.x >> 6;
#pragma unroll
    for (int rp = 0; rp < 16; ++rp) {
        int row = rp * 4 + rq;
        float w = W[(size_t)(j0 + row) * IN_DIM + i0 + c];
        tile[row][c] = w;
        Wb[(size_t)(j0 + row) * IN_DIM + i0 + c] = f2bf(w);
    }
    __syncthreads();
#pragma unroll
    for (int rp = 0; rp < 16; ++rp) {
        int row = rp * 4 + rq;
        WTb[(size_t)(i0 + row) * OUT_DIM + j0 + c] = f2bf(tile[c][row]);
    }
}

// ---------------------------------------------------------------------------
// Shared epilogue: per-wave LDS re-layout ([16][68] f32) -> coalesced I/O.
// MFMA C layout (m89): acc[m][n][i] -> row (lane>>4)*4+i, col n*16+(lane&15)
// ---------------------------------------------------------------------------
#define EPILOGUE(MR_)                                                          \
    float* lep = (float*)(smem + w * 4352);                                    \
    const int li = lane >> 4;                                                  \
    const int lc = lane & 15;                                                  \
    _Pragma("unroll")                                                          \
    for (int m = 0; m < (MR_); ++m) {                                          \
        _Pragma("unroll")                                                      \
        for (int n = 0; n < 4; ++n)                                            \
            _Pragma("unroll")                                                  \
            for (int i = 0; i < 4; ++i)                                        \
                lep[(li * 4 + i) * 68 + n * 16 + lc] = acc[m][n][i];           \
        asm volatile("s_waitcnt lgkmcnt(0)" ::: "memory");                     \
        __builtin_amdgcn_sched_barrier(0);                                     \
        _Pragma("unroll")                                                      \
        for (int rr = 0; rr < 4; ++rr) {                                       \
            const int row = rr + li * 4;                                       \
            float4 v = *reinterpret_cast<const float4*>(&lep[row * 68 + lc * 4]); \
            const size_t idx  = (size_t)(row0w + m * 16 + row) * N + col0w + lc * 4; \
            const size_t idx4 = idx >> 2;                                      \
            if constexpr (EPI == 0) {                                          \
                float4 iv = reinterpret_cast<const float4*>(inb)[idx4];        \
                ushort4 g;                                                     \
                g.x = f2bf(-0.05f * sqrtf(iv.x * iv.x + 1e-6f) * expf(-v.x));  \
                g.y = f2bf(-0.05f * sqrtf(iv.y * iv.y + 1e-6f) * expf(-v.y));  \
                g.z = f2bf(-0.05f * sqrtf(iv.z * iv.z + 1e-6f) * expf(-v.z));  \
                g.w = f2bf(-0.05f * sqrtf(iv.w * iv.w + 1e-6f) * expf(-v.w));  \
                *reinterpret_cast<ushort4*>(&Gb[idx]) = g;                     \
            } else if constexpr (EPI == 1) {                                   \
                float4 iv = reinterpret_cast<const float4*>(inb)[idx4];        \
                float4 o;                                                      \
                o.x = 0.05f * (1.0f + expf(-v.x)) * sqrtf(iv.x * iv.x + 1e-6f); \
                o.y = 0.05f * (1.0f + expf(-v.y)) * sqrtf(iv.y * iv.y + 1e-6f); \
                o.z = 0.05f * (1.0f + expf(-v.z)) * sqrtf(iv.z * iv.z + 1e-6f); \
                o.w = 0.05f * (1.0f + expf(-v.w)) * sqrtf(iv.w * iv.w + 1e-6f); \
                reinterpret_cast<float4*>(out)[idx4] = o;                      \
            } else {                                                           \
                ushort4 xu  = *reinterpret_cast<const ushort4*>(&xb[idx]);     \
                ushort4 a1u = *reinterpret_cast<const ushort4*>(&acc1[idx]);   \
                ushort4 a2u = *reinterpret_cast<const ushort4*>(&acc2[idx]);   \
                float xs[4] = {bf2f(xu.x), bf2f(xu.y), bf2f(xu.z), bf2f(xu.w)}; \
                float vs[4] = {v.x, v.y, v.z, v.w};                            \
                ushortT a1s[4] = {a1u.x, a1u.y, a1u.z, a1u.w};                 \
                ushortT a2s[4] = {a2u.x, a2u.y, a2u.z, a2u.w};                 \
                ushortT a1n[4], a2n[4], xbn[4];                                \
                _Pragma("unroll")                                              \
                for (int j = 0; j < 4; ++j) {                                  \
                    float g    = vs[j] + 0.02f * xs[j] + 0.1f * xs[j] * rsqrtf(xs[j] * xs[j] + 1e-6f); \
                    float a1   = 0.9f * bf2f(a1s[j]) + 0.1f * g * g;           \
                    float inv  = rsqrtf(a1 + 1e-8f);                           \
                    float r_   = 0.009f * g * inv;                             \
                    float a2   = 0.9f * bf2f(a2s[j]) - r_;                     \
                    float cand = xs[j] - r_;                                   \
                    float t_   = 0.0009f * inv;                                \
                    float xn   = fmaxf(cand - t_, 0.0f) + fminf(cand + t_, 0.0f) + 0.9f * a2; \
                    a1n[j] = f2bf(a1); a2n[j] = f2bf(a2); xbn[j] = f2bf(xn);   \
                }                                                              \
                *reinterpret_cast<ushort4*>(&acc1[idx]) = make_ushort4(a1n[0], a1n[1], a1n[2], a1n[3]); \
                *reinterpret_cast<ushort4*>(&acc2[idx]) = make_ushort4(a2n[0], a2n[1], a2n[2], a2n[3]); \
                *reinterpret_cast<ushort4*>(&xb[idx])   = make_ushort4(xbn[0], xbn[1], xbn[2], xbn[3]); \
            }                                                                  \
        }                                                                      \
        asm volatile("s_waitcnt lgkmcnt(0)" ::: "memory");                     \
    }

// ============================================================================
// KERNEL 1 (fwd/final, R7 winner): deep 4-phase pipeline, 1 blk/CU.
// BM=128, BN=256, 8 waves (2M x 4N), ring-4 BK=32, counted vmcnt.
// ============================================================================
#define PHASE(MB, RB, SLOTP, STTILE, C0, NC)                                   \
    {                                                                          \
        const char* sb_ = (SLOTP);                                             \
        if (RB) {                                                              \
            _Pragma("unroll")                                                  \
            for (int n = 0; n < 4; ++n)                                        \
                bF[n] = *reinterpret_cast<const bf16x8*>(sb_ + bRd[n]);        \
        }                                                                      \
        bf16x8 aF[4];                                                          \
        _Pragma("unroll")                                                      \
        for (int m = 0; m < 4; ++m)                                            \
            aF[m] = *reinterpret_cast<const bf16x8*>(sb_ + aRd[m]);            \
        if ((STTILE) < nt) {                                                   \
            _Pragma("unroll")                                                  \
            for (int c = 0; c < (NC); ++c) stage_chunk((STTILE), (C0) + c);    \
        }                                                                      \
        __builtin_amdgcn_sched_barrier(0);                                     \
        __builtin_amdgcn_s_barrier();                                          \
        asm volatile("s_waitcnt lgkmcnt(0)" ::: "memory");                     \
        __builtin_amdgcn_sched_barrier(0);                                     \
        __builtin_amdgcn_s_setprio(1);                                         \
        _Pragma("unroll")                                                      \
        for (int m = 0; m < 4; ++m) {                                          \
            _Pragma("unroll")                                                  \
            for (int n = 0; n < 4; ++n)                                        \
                acc[m][n] = __builtin_amdgcn_mfma_f32_16x16x32_bf16(           \
                    aF[m], bF[n], acc[m][n], 0, 0, 0);                         \
        }                                                                      \
        __builtin_amdgcn_s_setprio(0);                                         \
        __builtin_amdgcn_s_barrier();                                          \
        __builtin_amdgcn_sched_barrier(0);                                     \
    }

template <int EPI>
__global__ __launch_bounds__(512, 1)
void gemm_phase(const ushortT* __restrict__ A, const ushortT* __restrict__ Bm,
                int N, int K,
                const float* __restrict__ inb, ushortT* __restrict__ Gb,
                float* __restrict__ out,
                ushortT* __restrict__ acc1, ushortT* __restrict__ acc2,
                ushortT* __restrict__ xb) {
    constexpr int BM = 128, BN = 256;
    constexpr int ASZ  = BM * 64;
    constexpr int SLOT = ASZ + BN * 64;
    constexpr int LA   = 1, LB = 2, L = 3;
    __shared__ alignas(16) char smem[4 * SLOT];

    const int tid  = threadIdx.x;
    const int lane = tid & 63;
    const int w    = tid >> 6;
    const int wm   = w >> 2;
    const int wn   = w & 3;
    const int nbx  = N / BN;
    const int nwg  = gridDim.x;
    const int cpx  = nwg >> 3;
    const int bid  = (int)blockIdx.x;
    const int swz  = (bid & 7) * cpx + (bid >> 3);
    const int bx   = swz % nbx;
    const int by   = swz / nbx;
    const int row0 = by * BM;
    const int col0 = bx * BN;
    const size_t strideK2 = (size_t)K * 2;

    const char* gp[L]; int lo[L];
#pragma unroll
    for (int i = 0; i < LA; ++i) {
        int Lp  = i * 512 + tid;
        int row = Lp >> 2, sl = Lp & 3;
        int src = sl ^ ((row >> 1) & 3);
        gp[i] = (const char*)A + (size_t)(row0 + row) * strideK2 + src * 16;
        lo[i] = i * 8192 + w * 1024;
    }
#pragma unroll
    for (int i = 0; i < LB; ++i) {
        int Lp  = i * 512 + tid;
        int row = Lp >> 2, sl = Lp & 3;
        int src = sl ^ ((row >> 1) & 3);
        gp[LA + i] = (const char*)Bm + (size_t)(col0 + row) * strideK2 + src * 16;
        lo[LA + i] = ASZ + i * 8192 + w * 1024;
    }
    auto stage_all = [&](int tt) {
        char* sb = smem + (tt & 3) * SLOT;
        const size_t kb = (size_t)tt * 64;
#pragma unroll
        for (int c = 0; c < L; ++c) gload16(gp[c] + kb, sb + lo[c]);
    };
    auto stage_chunk = [&](int tt, int c) {
        gload16(gp[c] + (size_t)tt * 64, smem + (tt & 3) * SLOT + lo[c]);
    };

    int aRd[4], bRd[4];
#pragma unroll
    for (int m = 0; m < 4; ++m) {
        int row = wm * 64 + m * 16 + (lane & 15);
        aRd[m] = row * 64 + (((lane >> 4) ^ ((row >> 1) & 3)) * 16);
    }
#pragma unroll
    for (int n = 0; n < 4; ++n) {
        int row = wn * 64 + n * 16 + (lane & 15);
        bRd[n] = ASZ + row * 64 + (((lane >> 4) ^ ((row >> 1) & 3)) * 16);
    }

    f32x4 acc[4][4] = {};
    const int nt = K >> 5;

    stage_all(0); stage_all(1); stage_all(2);

    for (int tt = 0; tt < nt; tt += 2) {
        if (tt + 2 < nt) asm volatile("s_waitcnt vmcnt(%0)" :: "n"(L) : "memory");
        else             asm volatile("s_waitcnt vmcnt(0)"  ::: "memory");
        __builtin_amdgcn_s_barrier();
        __builtin_amdgcn_sched_barrier(0);

        const char* sb0 = smem + (tt & 3) * SLOT;
        const char* sb1 = smem + ((tt + 1) & 3) * SLOT;
        bf16x8 bF[4];
        PHASE(0, true, sb0, tt + 3, 0, 3)
        PHASE(0, true, sb1, tt + 4, 0, 3)
    }

    __builtin_amdgcn_s_barrier();
    const int row0w = row0 + wm * 64;
    const int col0w = col0 + wn * 64;
    EPILOGUE(4)
}

// ============================================================================
// KERNEL 2 (grad): ring-2 double-buffer, 48 KB LDS -> 3 blk/CU (24 waves/CU).
// BM=256, BN=128, 8 waves (4M x 2N). Per tile: {vmcnt(0); barrier; 8 ds_reads;
// stage(tt+1); setprio(1); 16 MFMA; setprio(0)}. TLP from 3 independent
// blocks fills the drain + staggers the big state-update epilogues.
// Hazards: WAR -- stage(tt+1) issues after pub-barrier(tt); every wave's
// iter-(tt-1) reads retired (lgkmcnt before MFMA) before it reached that
// barrier. RAW -- vmcnt(0)+barrier publishes tile tt to all waves.
// ============================================================================
template <int EPI>
__global__ __launch_bounds__(512, 4)
void gemm_mb2(const ushortT* __restrict__ A, const ushortT* __restrict__ Bm,
              int N, int K,
              const float* __restrict__ inb, ushortT* __restrict__ Gb,
              float* __restrict__ out,
              ushortT* __restrict__ acc1, ushortT* __restrict__ acc2,
              ushortT* __restrict__ xb) {
    constexpr int BM = 256, BN = 128;
    constexpr int ASZ  = BM * 64;
    constexpr int SLOT = ASZ + BN * 64;      // 24 KB
    constexpr int CA   = 2, CB = 1, L = 3;
    __shared__ alignas(16) char smem[2 * SLOT];

    const int tid  = threadIdx.x;
    const int lane = tid & 63;
    const int w    = tid >> 6;
    const int wm   = w >> 1;                 // 0..3 (M)
    const int wn   = w & 1;                  // 0..1 (N)
    const int nbx  = N / BN;
    const int nwg  = gridDim.x;
    const int cpx  = nwg >> 3;
    const int bid  = (int)blockIdx.x;
    const int swz  = (bid & 7) * cpx + (bid >> 3);
    const int bx   = swz % nbx;
    const int by   = swz / nbx;
    const int row0 = by * BM;
    const int col0 = bx * BN;
    const size_t strideK2 = (size_t)K * 2;

    const char* gp[L]; int lo[L];
#pragma unroll
    for (int c = 0; c < CA; ++c) {
        int Lp  = c * 512 + tid;
        int row = Lp >> 2, sl = Lp & 3;
        int src = sl ^ ((row >> 1) & 3);
        gp[c] = (const char*)A + (size_t)(row0 + row) * strideK2 + src * 16;
        lo[c] = c * 8192 + w * 1024;
    }
#pragma unroll
    for (int c = 0; c < CB; ++c) {
        int Lp  = c * 512 + tid;
        int row = Lp >> 2, sl = Lp & 3;
        int src = sl ^ ((row >> 1) & 3);
        gp[CA + c] = (const char*)Bm + (size_t)(col0 + row) * strideK2 + src * 16;
        lo[CA + c] = ASZ + c * 8192 + w * 1024;
    }
    auto stage = [&](int tt) {
        char* sb = smem + (tt & 1) * SLOT;
        const size_t kb = (size_t)tt * 64;
#pragma unroll
        for (int c = 0; c < L; ++c) gload16(gp[c] + kb, sb + lo[c]);
    };

    int aRd[4], bRd[4];
#pragma unroll
    for (int m = 0; m < 4; ++m) {
        int row = wm * 64 + m * 16 + (lane & 15);
        aRd[m] = row * 64 + (((lane >> 4) ^ ((row >> 1) & 3)) * 16);
    }
#pragma unroll
    for (int n = 0; n < 4; ++n) {
        int row = wn * 64 + n * 16 + (lane & 15);
        bRd[n] = ASZ + row * 64 + (((lane >> 4) ^ ((row >> 1) & 3)) * 16);
    }

    f32x4 acc[4][4] = {};
    const int nt = K >> 5;

    stage(0);

    for (int tt = 0; tt < nt; ++tt) {
        asm volatile("s_waitcnt vmcnt(0)" ::: "memory");
        __builtin_amdgcn_s_barrier();        // pub(tt)
        __builtin_amdgcn_sched_barrier(0);

        const char* sb = smem + (tt & 1) * SLOT;
        bf16x8 aF[4], bF[4];
#pragma unroll
        for (int n = 0; n < 4; ++n) bF[n] = *reinterpret_cast<const bf16x8*>(sb + bRd[n]);
#pragma unroll
        for (int m = 0; m < 4; ++m) aF[m] = *reinterpret_cast<const bf16x8*>(sb + aRd[m]);
        if (tt + 1 < nt) stage(tt + 1);      // after pub barrier -> WAR-safe
        __builtin_amdgcn_s_setprio(1);
#pragma unroll
        for (int m = 0; m < 4; ++m)
#pragma unroll
            for (int n = 0; n < 4; ++n)
                acc[m][n] = __builtin_amdgcn_mfma_f32_16x16x32_bf16(aF[m], bF[n], acc[m][n], 0, 0, 0);
        __builtin_amdgcn_s_setprio(0);
    }

    __builtin_amdgcn_s_barrier();            // reads retired; reuse LDS
    const int row0w = row0 + wm * 64;
    const int col0w = col0 + wn * 64;
    EPILOGUE(4)
}

extern "C" void kernel_launch(void* const* d_in, const int* in_sizes, int n_in,
                              void* d_out, int out_size, void* d_ws, size_t ws_size,
                              hipStream_t stream) {
    const float* in = (const float*)d_in[0];
    const float* W  = (const float*)d_in[1];
    float* out = (float*)d_out;
    char* ws = (char*)d_ws;

    // workspace layout — 144 MB total (state first for one contiguous memset)
    ushortT* acc1 = (ushortT*)(ws);                            // 32 MB bf16 [4096,4096]
    ushortT* acc2 = (ushortT*)(ws + ((size_t)32  << 20));      // 32 MB bf16
    ushortT* xb   = (ushortT*)(ws + ((size_t)64  << 20));      // 32 MB bf16
    ushortT* Wb   = (ushortT*)(ws + ((size_t)96  << 20));      // 16 MB bf16 [4096,2048]
    ushortT* WTb  = (ushortT*)(ws + ((size_t)112 << 20));      // 16 MB bf16 [2048,4096]
    ushortT* Gb   = (ushortT*)(ws + ((size_t)128 << 20));      // 16 MB bf16 [4096,2048]

    hipMemsetAsync(ws, 0, (size_t)96 << 20, stream);           // acc1, acc2, xb = 0

    prep_g0_kernel<<<dim3(B_DIM * IN_DIM / 4 / 256), dim3(256), 0, stream>>>(in, Gb);
    conv_w_kernel<<<dim3(IN_DIM / 64, OUT_DIM / 64), dim3(256), 0, stream>>>(W, Wb, WTb);

    // fwd/final: BM=128,BN=256 -> 32x8  = 256 blocks (deep pipeline, 1 blk/CU)
    // grad:      BM=256,BN=128 -> 16x32 = 512 blocks (ring-2, 3 blk/CU)
    for (int step = 0; step < 9; ++step) {
        if (step > 0) {
            gemm_phase<0><<<dim3(256), dim3(512), 0, stream>>>(
                xb, WTb, IN_DIM, OUT_DIM, in, Gb, nullptr, nullptr, nullptr, nullptr);
        }
        gemm_mb2<2><<<dim3(512), dim3(512), 0, stream>>>(
            Gb, Wb, OUT_DIM, IN_DIM, nullptr, nullptr, nullptr, acc1, acc2, xb);
    }
    gemm_phase<1><<<dim3(256), dim3(512), 0, stream>>>(
        xb, WTb, IN_DIM, OUT_DIM, in, nullptr, out, nullptr, nullptr, nullptr);
}

// Round 10
// 1562.592 us; speedup vs baseline: 1.0641x; 1.0084x over previous
//
#include <hip/hip_runtime.h>
#include <cstdint>
#include <cstddef>

#define B_DIM   4096
#define IN_DIM  2048
#define OUT_DIM 4096

typedef __attribute__((ext_vector_type(8))) __bf16 bf16x8;
typedef __attribute__((ext_vector_type(4))) float  f32x4;
typedef unsigned short ushortT;

__device__ __forceinline__ ushortT f2bf(float f) {
    unsigned int u = __float_as_uint(f);
    u += 0x7FFFu + ((u >> 16) & 1u);          // round-to-nearest-even
    return (ushortT)(u >> 16);
}
__device__ __forceinline__ float bf2f(ushortT b) {
    return __uint_as_float(((unsigned int)b) << 16);
}

// global -> LDS direct DMA, 16 B per lane (wave-uniform LDS base, lane i at +i*16).
__device__ __forceinline__ void gload16(const void* g, void* l) {
    __builtin_amdgcn_global_load_lds(
        (const __attribute__((address_space(1))) void*)g,
        (__attribute__((address_space(3))) void*)l, 16, 0, 0);
}

// negA = Gb0 = bf16(-0.05 * sqrt(in^2 + 1e-6))   (step-0 gradient: exp(-0)=1)
__global__ void prep_g0_kernel(const float* __restrict__ in, ushortT* __restrict__ Gb,
                               ushortT* __restrict__ negA) {
    int i = blockIdx.x * 256 + threadIdx.x;
    float4 v = reinterpret_cast<const float4*>(in)[i];
    ushort4 g;
    g.x = f2bf(-0.05f * sqrtf(v.x * v.x + 1e-6f));
    g.y = f2bf(-0.05f * sqrtf(v.y * v.y + 1e-6f));
    g.z = f2bf(-0.05f * sqrtf(v.z * v.z + 1e-6f));
    g.w = f2bf(-0.05f * sqrtf(v.w * v.w + 1e-6f));
    reinterpret_cast<ushort4*>(Gb)[i]   = g;
    reinterpret_cast<ushort4*>(negA)[i] = g;
}

// Wb = bf16(W) [OUT][IN];  WTb = bf16(W^T) [IN][OUT]
__global__ void conv_w_kernel(const float* __restrict__ W, ushortT* __restrict__ Wb,
                              ushortT* __restrict__ WTb) {
    __shared__ float tile[64][65];
    const int i0 = blockIdx.x * 64;
    const int j0 = blockIdx.y * 64;
    const int c  = threadIdx.x & 63;
    const int rq = threadIdx.x >> 6;
#pragma unroll
    for (int rp = 0; rp < 16; ++rp) {
        int row = rp * 4 + rq;
        float w = W[(size_t)(j0 + row) * IN_DIM + i0 + c];
        tile[row][c] = w;
        Wb[(size_t)(j0 + row) * IN_DIM + i0 + c] = f2bf(w);
    }
    __syncthreads();
#pragma unroll
    for (int rp = 0; rp < 16; ++rp) {
        int row = rp * 4 + rq;
        WTb[(size_t)(i0 + row) * OUT_DIM + j0 + c] = f2bf(tile[c][row]);
    }
}

// ---------------------------------------------------------------------------
// Shared epilogue: per-wave LDS re-layout ([16][68] f32) -> coalesced I/O.
// MFMA C layout (m89): acc[m][n][i] -> row (lane>>4)*4+i, col n*16+(lane&15)
//  EPI 0: Gb = bf16(negA * exp(-acc))          (negA = bf16(-0.05*a), 1 load)
//  EPI 1: out = 0.05*(1+exp(-acc))*sqrt(in^2+1e-6)   (fp32 recompute, final)
//  EPI 2: fused RMSProp + prox update of bf16 state xb/acc1/acc2
// ---------------------------------------------------------------------------
#define EPILOGUE(MR_)                                                          \
    float* lep = (float*)(smem + w * 4352);                                    \
    const int li = lane >> 4;                                                  \
    const int lc = lane & 15;                                                  \
    _Pragma("unroll")                                                          \
    for (int m = 0; m < (MR_); ++m) {                                          \
        _Pragma("unroll")                                                      \
        for (int n = 0; n < 4; ++n)                                            \
            _Pragma("unroll")                                                  \
            for (int i = 0; i < 4; ++i)                                        \
                lep[(li * 4 + i) * 68 + n * 16 + lc] = acc[m][n][i];           \
        asm volatile("s_waitcnt lgkmcnt(0)" ::: "memory");                     \
        __builtin_amdgcn_sched_barrier(0);                                     \
        _Pragma("unroll")                                                      \
        for (int rr = 0; rr < 4; ++rr) {                                       \
            const int row = rr + li * 4;                                       \
            float4 v = *reinterpret_cast<const float4*>(&lep[row * 68 + lc * 4]); \
            const size_t idx  = (size_t)(row0w + m * 16 + row) * N + col0w + lc * 4; \
            const size_t idx4 = idx >> 2;                                      \
            if constexpr (EPI == 0) {                                          \
                ushort4 au = *reinterpret_cast<const ushort4*>(&nega[idx]);    \
                ushort4 g;                                                     \
                g.x = f2bf(bf2f(au.x) * expf(-v.x));                           \
                g.y = f2bf(bf2f(au.y) * expf(-v.y));                           \
                g.z = f2bf(bf2f(au.z) * expf(-v.z));                           \
                g.w = f2bf(bf2f(au.w) * expf(-v.w));                           \
                *reinterpret_cast<ushort4*>(&Gb[idx]) = g;                     \
            } else if constexpr (EPI == 1) {                                   \
                float4 iv = reinterpret_cast<const float4*>(inb)[idx4];        \
                float4 o;                                                      \
                o.x = 0.05f * (1.0f + expf(-v.x)) * sqrtf(iv.x * iv.x + 1e-6f); \
                o.y = 0.05f * (1.0f + expf(-v.y)) * sqrtf(iv.y * iv.y + 1e-6f); \
                o.z = 0.05f * (1.0f + expf(-v.z)) * sqrtf(iv.z * iv.z + 1e-6f); \
                o.w = 0.05f * (1.0f + expf(-v.w)) * sqrtf(iv.w * iv.w + 1e-6f); \
                reinterpret_cast<float4*>(out)[idx4] = o;                      \
            } else {                                                           \
                ushort4 xu  = *reinterpret_cast<const ushort4*>(&xb[idx]);     \
                ushort4 a1u = *reinterpret_cast<const ushort4*>(&acc1[idx]);   \
                ushort4 a2u = *reinterpret_cast<const ushort4*>(&acc2[idx]);   \
                float xs[4] = {bf2f(xu.x), bf2f(xu.y), bf2f(xu.z), bf2f(xu.w)}; \
                float vs[4] = {v.x, v.y, v.z, v.w};                            \
                ushortT a1s[4] = {a1u.x, a1u.y, a1u.z, a1u.w};                 \
                ushortT a2s[4] = {a2u.x, a2u.y, a2u.z, a2u.w};                 \
                ushortT a1n[4], a2n[4], xbn[4];                                \
                _Pragma("unroll")                                              \
                for (int j = 0; j < 4; ++j) {                                  \
                    float g    = vs[j] + 0.02f * xs[j] + 0.1f * xs[j] * rsqrtf(xs[j] * xs[j] + 1e-6f); \
                    float a1   = 0.9f * bf2f(a1s[j]) + 0.1f * g * g;           \
                    float inv  = rsqrtf(a1 + 1e-8f);                           \
                    float r_   = 0.009f * g * inv;                             \
                    float a2   = 0.9f * bf2f(a2s[j]) - r_;                     \
                    float cand = xs[j] - r_;                                   \
                    float t_   = 0.0009f * inv;                                \
                    float xn   = fmaxf(cand - t_, 0.0f) + fminf(cand + t_, 0.0f) + 0.9f * a2; \
                    a1n[j] = f2bf(a1); a2n[j] = f2bf(a2); xbn[j] = f2bf(xn);   \
                }                                                              \
                *reinterpret_cast<ushort4*>(&acc1[idx]) = make_ushort4(a1n[0], a1n[1], a1n[2], a1n[3]); \
                *reinterpret_cast<ushort4*>(&acc2[idx]) = make_ushort4(a2n[0], a2n[1], a2n[2], a2n[3]); \
                *reinterpret_cast<ushort4*>(&xb[idx])   = make_ushort4(xbn[0], xbn[1], xbn[2], xbn[3]); \
            }                                                                  \
        }                                                                      \
        asm volatile("s_waitcnt lgkmcnt(0)" ::: "memory");                     \
    }

// ============================================================================
// KERNEL 1 (fwd/final — R7 winner): deep 4-phase pipeline, 1 blk/CU.
// BM=128, BN=256, 8 waves (2M x 4N), ring-4 BK=32, counted vmcnt.
// ============================================================================
#define PHASE(MB, RB, SLOTP, STTILE, C0, NC)                                   \
    {                                                                          \
        const char* sb_ = (SLOTP);                                             \
        if (RB) {                                                              \
            _Pragma("unroll")                                                  \
            for (int n = 0; n < 4; ++n)                                        \
                bF[n] = *reinterpret_cast<const bf16x8*>(sb_ + bRd[n]);        \
        }                                                                      \
        bf16x8 aF[4];                                                          \
        _Pragma("unroll")                                                      \
        for (int m = 0; m < 4; ++m)                                            \
            aF[m] = *reinterpret_cast<const bf16x8*>(sb_ + aRd[m]);            \
        if ((STTILE) < nt) {                                                   \
            _Pragma("unroll")                                                  \
            for (int c = 0; c < (NC); ++c) stage_chunk((STTILE), (C0) + c);    \
        }                                                                      \
        __builtin_amdgcn_sched_barrier(0);                                     \
        __builtin_amdgcn_s_barrier();                                          \
        asm volatile("s_waitcnt lgkmcnt(0)" ::: "memory");                     \
        __builtin_amdgcn_sched_barrier(0);                                     \
        __builtin_amdgcn_s_setprio(1);                                         \
        _Pragma("unroll")                                                      \
        for (int m = 0; m < 4; ++m) {                                          \
            _Pragma("unroll")                                                  \
            for (int n = 0; n < 4; ++n)                                        \
                acc[m][n] = __builtin_amdgcn_mfma_f32_16x16x32_bf16(           \
                    aF[m], bF[n], acc[m][n], 0, 0, 0);                         \
        }                                                                      \
        __builtin_amdgcn_s_setprio(0);                                         \
        __builtin_amdgcn_s_barrier();                                          \
        __builtin_amdgcn_sched_barrier(0);                                     \
    }

template <int EPI>
__global__ __launch_bounds__(512, 1)
void gemm_phase(const ushortT* __restrict__ A, const ushortT* __restrict__ Bm,
                int N, int K,
                const float* __restrict__ inb, const ushortT* __restrict__ nega,
                ushortT* __restrict__ Gb, float* __restrict__ out,
                ushortT* __restrict__ acc1, ushortT* __restrict__ acc2,
                ushortT* __restrict__ xb) {
    constexpr int BM = 128, BN = 256;
    constexpr int ASZ  = BM * 64;
    constexpr int SLOT = ASZ + BN * 64;
    constexpr int LA   = 1, LB = 2, L = 3;
    __shared__ alignas(16) char smem[4 * SLOT];

    const int tid  = threadIdx.x;
    const int lane = tid & 63;
    const int w    = tid >> 6;
    const int wm   = w >> 2;
    const int wn   = w & 3;
    const int nbx  = N / BN;
    const int nwg  = gridDim.x;
    const int cpx  = nwg >> 3;
    const int bid  = (int)blockIdx.x;
    const int swz  = (bid & 7) * cpx + (bid >> 3);
    const int bx   = swz % nbx;
    const int by   = swz / nbx;
    const int row0 = by * BM;
    const int col0 = bx * BN;
    const size_t strideK2 = (size_t)K * 2;

    const char* gp[L]; int lo[L];
#pragma unroll
    for (int i = 0; i < LA; ++i) {
        int Lp  = i * 512 + tid;
        int row = Lp >> 2, sl = Lp & 3;
        int src = sl ^ ((row >> 1) & 3);
        gp[i] = (const char*)A + (size_t)(row0 + row) * strideK2 + src * 16;
        lo[i] = i * 8192 + w * 1024;
    }
#pragma unroll
    for (int i = 0; i < LB; ++i) {
        int Lp  = i * 512 + tid;
        int row = Lp >> 2, sl = Lp & 3;
        int src = sl ^ ((row >> 1) & 3);
        gp[LA + i] = (const char*)Bm + (size_t)(col0 + row) * strideK2 + src * 16;
        lo[LA + i] = ASZ + i * 8192 + w * 1024;
    }
    auto stage_all = [&](int tt) {
        char* sb = smem + (tt & 3) * SLOT;
        const size_t kb = (size_t)tt * 64;
#pragma unroll
        for (int c = 0; c < L; ++c) gload16(gp[c] + kb, sb + lo[c]);
    };
    auto stage_chunk = [&](int tt, int c) {
        gload16(gp[c] + (size_t)tt * 64, smem + (tt & 3) * SLOT + lo[c]);
    };

    int aRd[4], bRd[4];
#pragma unroll
    for (int m = 0; m < 4; ++m) {
        int row = wm * 64 + m * 16 + (lane & 15);
        aRd[m] = row * 64 + (((lane >> 4) ^ ((row >> 1) & 3)) * 16);
    }
#pragma unroll
    for (int n = 0; n < 4; ++n) {
        int row = wn * 64 + n * 16 + (lane & 15);
        bRd[n] = ASZ + row * 64 + (((lane >> 4) ^ ((row >> 1) & 3)) * 16);
    }

    f32x4 acc[4][4] = {};
    const int nt = K >> 5;

    stage_all(0); stage_all(1); stage_all(2);

    for (int tt = 0; tt < nt; tt += 2) {
        if (tt + 2 < nt) asm volatile("s_waitcnt vmcnt(%0)" :: "n"(L) : "memory");
        else             asm volatile("s_waitcnt vmcnt(0)"  ::: "memory");
        __builtin_amdgcn_s_barrier();
        __builtin_amdgcn_sched_barrier(0);

        const char* sb0 = smem + (tt & 3) * SLOT;
        const char* sb1 = smem + ((tt + 1) & 3) * SLOT;
        bf16x8 bF[4];
        PHASE(0, true, sb0, tt + 3, 0, 3)
        PHASE(0, true, sb1, tt + 4, 0, 3)
    }

    __builtin_amdgcn_s_barrier();
    const int row0w = row0 + wm * 64;
    const int col0w = col0 + wn * 64;
    EPILOGUE(4)
}

// ============================================================================
// KERNEL 2 (grad — R8 winner): ring-3, counted vmcnt(3), 72 KB -> 2 blk/CU.
// BM=256, BN=128, 8 waves (4M x 2N). Per tile: {vmcnt(L) [0 at tail]; barrier;
// 8 ds_reads; stage(tt+2); setprio(1); 16 MFMA; setprio(0)}.
// Hazards: RAW -- vmcnt(L)+barrier forces slot tt complete (tt+1 in flight).
//   WAR -- stage(tt+2) -> slot (tt-1)%3 issues after pub(tt) barrier, which
//   follows every wave's slot-(tt-1) reads (lgkmcnt before MFMA, prev iter).
// ============================================================================
template <int EPI>
__global__ __launch_bounds__(512, 4)
void gemm_mb(const ushortT* __restrict__ A, const ushortT* __restrict__ Bm,
             int N, int K,
             const float* __restrict__ inb, const ushortT* __restrict__ nega,
             ushortT* __restrict__ Gb, float* __restrict__ out,
             ushortT* __restrict__ acc1, ushortT* __restrict__ acc2,
             ushortT* __restrict__ xb) {
    constexpr int BM = 256, BN = 128;
    constexpr int ASZ  = BM * 64;
    constexpr int SLOT = ASZ + BN * 64;      // 24 KB
    constexpr int CA   = 2, CB = 1, L = 3;
    __shared__ alignas(16) char smem[3 * SLOT];

    const int tid  = threadIdx.x;
    const int lane = tid & 63;
    const int w    = tid >> 6;
    const int wm   = w >> 1;                 // 0..3 (M)
    const int wn   = w & 1;                  // 0..1 (N)
    const int nbx  = N / BN;
    const int nwg  = gridDim.x;
    const int cpx  = nwg >> 3;
    const int bid  = (int)blockIdx.x;
    const int swz  = (bid & 7) * cpx + (bid >> 3);
    const int bx   = swz % nbx;
    const int by   = swz / nbx;
    const int row0 = by * BM;
    const int col0 = bx * BN;
    const size_t strideK2 = (size_t)K * 2;

    const char* gp[L]; int lo[L];
#pragma unroll
    for (int c = 0; c < CA; ++c) {
        int Lp  = c * 512 + tid;
        int row = Lp >> 2, sl = Lp & 3;
        int src = sl ^ ((row >> 1) & 3);
        gp[c] = (const char*)A + (size_t)(row0 + row) * strideK2 + src * 16;
        lo[c] = c * 8192 + w * 1024;
    }
#pragma unroll
    for (int c = 0; c < CB; ++c) {
        int Lp  = c * 512 + tid;
        int row = Lp >> 2, sl = Lp & 3;
        int src = sl ^ ((row >> 1) & 3);
        gp[CA + c] = (const char*)Bm + (size_t)(col0 + row) * strideK2 + src * 16;
        lo[CA + c] = ASZ + c * 8192 + w * 1024;
    }
    auto stage = [&](int tt) {
        char* sb = smem + (tt % 3) * SLOT;
        const size_t kb = (size_t)tt * 64;
#pragma unroll
        for (int c = 0; c < L; ++c) gload16(gp[c] + kb, sb + lo[c]);
    };

    int aRd[4], bRd[4];
#pragma unroll
    for (int m = 0; m < 4; ++m) {
        int row = wm * 64 + m * 16 + (lane & 15);
        aRd[m] = row * 64 + (((lane >> 4) ^ ((row >> 1) & 3)) * 16);
    }
#pragma unroll
    for (int n = 0; n < 4; ++n) {
        int row = wn * 64 + n * 16 + (lane & 15);
        bRd[n] = ASZ + row * 64 + (((lane >> 4) ^ ((row >> 1) & 3)) * 16);
    }

    f32x4 acc[4][4] = {};
    const int nt = K >> 5;

    stage(0); stage(1);                      // prologue: 2 tiles in flight

    for (int tt = 0; tt < nt; ++tt) {
        if (tt < nt - 1) asm volatile("s_waitcnt vmcnt(%0)" :: "n"(L) : "memory");
        else             asm volatile("s_waitcnt vmcnt(0)"  ::: "memory");
        __builtin_amdgcn_s_barrier();        // pub(tt)
        __builtin_amdgcn_sched_barrier(0);

        const char* sb = smem + (tt % 3) * SLOT;
        bf16x8 aF[4], bF[4];
#pragma unroll
        for (int n = 0; n < 4; ++n) bF[n] = *reinterpret_cast<const bf16x8*>(sb + bRd[n]);
#pragma unroll
        for (int m = 0; m < 4; ++m) aF[m] = *reinterpret_cast<const bf16x8*>(sb + aRd[m]);
        if (tt + 2 < nt) stage(tt + 2);      // after pub barrier -> WAR-safe
        __builtin_amdgcn_s_setprio(1);
#pragma unroll
        for (int m = 0; m < 4; ++m)
#pragma unroll
            for (int n = 0; n < 4; ++n)
                acc[m][n] = __builtin_amdgcn_mfma_f32_16x16x32_bf16(aF[m], bF[n], acc[m][n], 0, 0, 0);
        __builtin_amdgcn_s_setprio(0);
    }

    __builtin_amdgcn_s_barrier();            // reads retired; reuse LDS
    const int row0w = row0 + wm * 64;
    const int col0w = col0 + wn * 64;
    EPILOGUE(4)
}

extern "C" void kernel_launch(void* const* d_in, const int* in_sizes, int n_in,
                              void* d_out, int out_size, void* d_ws, size_t ws_size,
                              hipStream_t stream) {
    const float* in = (const float*)d_in[0];
    const float* W  = (const float*)d_in[1];
    float* out = (float*)d_out;
    char* ws = (char*)d_ws;

    // workspace layout — 160 MB total (state first for one contiguous memset)
    ushortT* acc1 = (ushortT*)(ws);                            // 32 MB bf16 [4096,4096]
    ushortT* acc2 = (ushortT*)(ws + ((size_t)32  << 20));      // 32 MB bf16
    ushortT* xb   = (ushortT*)(ws + ((size_t)64  << 20));      // 32 MB bf16
    ushortT* Wb   = (ushortT*)(ws + ((size_t)96  << 20));      // 16 MB bf16 [4096,2048]
    ushortT* WTb  = (ushortT*)(ws + ((size_t)112 << 20));      // 16 MB bf16 [2048,4096]
    ushortT* Gb   = (ushortT*)(ws + ((size_t)128 << 20));      // 16 MB bf16 [4096,2048]
    ushortT* negA = (ushortT*)(ws + ((size_t)144 << 20));      // 16 MB bf16 [4096,2048]

    hipMemsetAsync(ws, 0, (size_t)96 << 20, stream);           // acc1, acc2, xb = 0

    prep_g0_kernel<<<dim3(B_DIM * IN_DIM / 4 / 256), dim3(256), 0, stream>>>(in, Gb, negA);
    conv_w_kernel<<<dim3(IN_DIM / 64, OUT_DIM / 64), dim3(256), 0, stream>>>(W, Wb, WTb);

    // fwd/final: BM=128,BN=256 -> 32x8  = 256 blocks (deep pipeline, 1 blk/CU)
    // grad:      BM=256,BN=128 -> 16x32 = 512 blocks (ring-3 counted, 2 blk/CU)
    for (int step = 0; step < 9; ++step) {
        if (step > 0) {
            gemm_phase<0><<<dim3(256), dim3(512), 0, stream>>>(
                xb, WTb, IN_DIM, OUT_DIM, nullptr, negA, Gb, nullptr, nullptr, nullptr, nullptr);
        }
        gemm_mb<2><<<dim3(512), dim3(512), 0, stream>>>(
            Gb, Wb, OUT_DIM, IN_DIM, nullptr, nullptr, nullptr, nullptr, acc1, acc2, xb);
    }
    gemm_phase<1><<<dim3(256), dim3(512), 0, stream>>>(
        xb, WTb, IN_DIM, OUT_DIM, in, nullptr, nullptr, out, nullptr, nullptr, nullptr);
}

// Round 11
// 1535.718 us; speedup vs baseline: 1.0827x; 1.0175x over previous
//
#include <hip/hip_runtime.h>
#include <cstdint>
#include <cstddef>

#define B_DIM   4096
#define IN_DIM  2048
#define OUT_DIM 4096

typedef __attribute__((ext_vector_type(8))) __bf16 bf16x8;
typedef __attribute__((ext_vector_type(4))) float  f32x4;
typedef unsigned short ushortT;

__device__ __forceinline__ ushortT f2bf(float f) {
    unsigned int u = __float_as_uint(f);
    u += 0x7FFFu + ((u >> 16) & 1u);          // round-to-nearest-even
    return (ushortT)(u >> 16);
}
__device__ __forceinline__ float bf2f(ushortT b) {
    return __uint_as_float(((unsigned int)b) << 16);
}

// global -> LDS direct DMA, 16 B per lane (wave-uniform LDS base, lane i at +i*16).
__device__ __forceinline__ void gload16(const void* g, void* l) {
    __builtin_amdgcn_global_load_lds(
        (const __attribute__((address_space(1))) void*)g,
        (__attribute__((address_space(3))) void*)l, 16, 0, 0);
}

// negA = Gb0 = bf16(-0.05 * sqrt(in^2 + 1e-6))   (step-0 gradient: exp(-0)=1)
__global__ void prep_g0_kernel(const float* __restrict__ in, ushortT* __restrict__ Gb,
                               ushortT* __restrict__ negA) {
    int i = blockIdx.x * 256 + threadIdx.x;
    float4 v = reinterpret_cast<const float4*>(in)[i];
    ushort4 g;
    g.x = f2bf(-0.05f * sqrtf(v.x * v.x + 1e-6f));
    g.y = f2bf(-0.05f * sqrtf(v.y * v.y + 1e-6f));
    g.z = f2bf(-0.05f * sqrtf(v.z * v.z + 1e-6f));
    g.w = f2bf(-0.05f * sqrtf(v.w * v.w + 1e-6f));
    reinterpret_cast<ushort4*>(Gb)[i]   = g;
    reinterpret_cast<ushort4*>(negA)[i] = g;
}

// Wb = bf16(W) [OUT][IN];  WTb = bf16(W^T) [IN][OUT]
__global__ void conv_w_kernel(const float* __restrict__ W, ushortT* __restrict__ Wb,
                              ushortT* __restrict__ WTb) {
    __shared__ float tile[64][65];
    const int i0 = blockIdx.x * 64;
    const int j0 = blockIdx.y * 64;
    const int c  = threadIdx.x & 63;
    const int rq = threadIdx.x >> 6;
#pragma unroll
    for (int rp = 0; rp < 16; ++rp) {
        int row = rp * 4 + rq;
        float w = W[(size_t)(j0 + row) * IN_DIM + i0 + c];
        tile[row][c] = w;
        Wb[(size_t)(j0 + row) * IN_DIM + i0 + c] = f2bf(w);
    }
    __syncthreads();
#pragma unroll
    for (int rp = 0; rp < 16; ++rp) {
        int row = rp * 4 + rq;
        WTb[(size_t)(i0 + row) * OUT_DIM + j0 + c] = f2bf(tile[c][row]);
    }
}

// ---------------------------------------------------------------------------
// Shared epilogue: per-wave LDS re-layout ([16][68] f32) -> coalesced I/O.
// MFMA C layout (m89): acc[m][n][i] -> row (lane>>4)*4+i, col n*16+(lane&15)
//  EPI 0: Gb = bf16(negA * exp(-acc))
//  EPI 1: out = 0.05*(1+exp(-acc))*sqrt(in^2+1e-6)
//  EPI 2: fused RMSProp + prox update of bf16 state xb/acc1/acc2
//  EPI 3: step-0 update (x=a1=a2=0): NO state reads, writes all state
// ---------------------------------------------------------------------------
#define EPILOGUE(MR_)                                                          \
    float* lep = (float*)(smem + w * 4352);                                    \
    const int li = lane >> 4;                                                  \
    const int lc = lane & 15;                                                  \
    _Pragma("unroll")                                                          \
    for (int m = 0; m < (MR_); ++m) {                                          \
        _Pragma("unroll")                                                      \
        for (int n = 0; n < 4; ++n)                                            \
            _Pragma("unroll")                                                  \
            for (int i = 0; i < 4; ++i)                                        \
                lep[(li * 4 + i) * 68 + n * 16 + lc] = acc[m][n][i];           \
        asm volatile("s_waitcnt lgkmcnt(0)" ::: "memory");                     \
        __builtin_amdgcn_sched_barrier(0);                                     \
        _Pragma("unroll")                                                      \
        for (int rr = 0; rr < 4; ++rr) {                                       \
            const int row = rr + li * 4;                                       \
            float4 v = *reinterpret_cast<const float4*>(&lep[row * 68 + lc * 4]); \
            const size_t idx  = (size_t)(row0w + m * 16 + row) * N + col0w + lc * 4; \
            const size_t idx4 = idx >> 2;                                      \
            if constexpr (EPI == 0) {                                          \
                ushort4 au = *reinterpret_cast<const ushort4*>(&nega[idx]);    \
                ushort4 g;                                                     \
                g.x = f2bf(bf2f(au.x) * __expf(-v.x));                         \
                g.y = f2bf(bf2f(au.y) * __expf(-v.y));                         \
                g.z = f2bf(bf2f(au.z) * __expf(-v.z));                         \
                g.w = f2bf(bf2f(au.w) * __expf(-v.w));                         \
                *reinterpret_cast<ushort4*>(&Gb[idx]) = g;                     \
            } else if constexpr (EPI == 1) {                                   \
                float4 iv = reinterpret_cast<const float4*>(inb)[idx4];        \
                float4 o;                                                      \
                o.x = 0.05f * (1.0f + expf(-v.x)) * sqrtf(iv.x * iv.x + 1e-6f); \
                o.y = 0.05f * (1.0f + expf(-v.y)) * sqrtf(iv.y * iv.y + 1e-6f); \
                o.z = 0.05f * (1.0f + expf(-v.z)) * sqrtf(iv.z * iv.z + 1e-6f); \
                o.w = 0.05f * (1.0f + expf(-v.w)) * sqrtf(iv.w * iv.w + 1e-6f); \
                reinterpret_cast<float4*>(out)[idx4] = o;                      \
            } else if constexpr (EPI == 3) {                                   \
                float vs[4] = {v.x, v.y, v.z, v.w};                            \
                ushortT a1n[4], a2n[4], xbn[4];                                \
                _Pragma("unroll")                                              \
                for (int j = 0; j < 4; ++j) {                                  \
                    float g    = vs[j];                                        \
                    float a1   = 0.1f * g * g;                                 \
                    float inv  = rsqrtf(a1 + 1e-8f);                           \
                    float r_   = 0.009f * g * inv;                             \
                    float a2   = -r_;                                          \
                    float cand = -r_;                                          \
                    float t_   = 0.0009f * inv;                                \
                    float xn   = fmaxf(cand - t_, 0.0f) + fminf(cand + t_, 0.0f) + 0.9f * a2; \
                    a1n[j] = f2bf(a1); a2n[j] = f2bf(a2); xbn[j] = f2bf(xn);   \
                }                                                              \
                *reinterpret_cast<ushort4*>(&acc1[idx]) = make_ushort4(a1n[0], a1n[1], a1n[2], a1n[3]); \
                *reinterpret_cast<ushort4*>(&acc2[idx]) = make_ushort4(a2n[0], a2n[1], a2n[2], a2n[3]); \
                *reinterpret_cast<ushort4*>(&xb[idx])   = make_ushort4(xbn[0], xbn[1], xbn[2], xbn[3]); \
            } else {                                                           \
                ushort4 xu  = *reinterpret_cast<const ushort4*>(&xb[idx]);     \
                ushort4 a1u = *reinterpret_cast<const ushort4*>(&acc1[idx]);   \
                ushort4 a2u = *reinterpret_cast<const ushort4*>(&acc2[idx]);   \
                float xs[4] = {bf2f(xu.x), bf2f(xu.y), bf2f(xu.z), bf2f(xu.w)}; \
                float vs[4] = {v.x, v.y, v.z, v.w};                            \
                ushortT a1s[4] = {a1u.x, a1u.y, a1u.z, a1u.w};                 \
                ushortT a2s[4] = {a2u.x, a2u.y, a2u.z, a2u.w};                 \
                ushortT a1n[4], a2n[4], xbn[4];                                \
                _Pragma("unroll")                                              \
                for (int j = 0; j < 4; ++j) {                                  \
                    float g    = vs[j] + 0.02f * xs[j] + 0.1f * xs[j] * rsqrtf(xs[j] * xs[j] + 1e-6f); \
                    float a1   = 0.9f * bf2f(a1s[j]) + 0.1f * g * g;           \
                    float inv  = rsqrtf(a1 + 1e-8f);                           \
                    float r_   = 0.009f * g * inv;                             \
                    float a2   = 0.9f * bf2f(a2s[j]) - r_;                     \
                    float cand = xs[j] - r_;                                   \
                    float t_   = 0.0009f * inv;                                \
                    float xn   = fmaxf(cand - t_, 0.0f) + fminf(cand + t_, 0.0f) + 0.9f * a2; \
                    a1n[j] = f2bf(a1); a2n[j] = f2bf(a2); xbn[j] = f2bf(xn);   \
                }                                                              \
                *reinterpret_cast<ushort4*>(&acc1[idx]) = make_ushort4(a1n[0], a1n[1], a1n[2], a1n[3]); \
                *reinterpret_cast<ushort4*>(&acc2[idx]) = make_ushort4(a2n[0], a2n[1], a2n[2], a2n[3]); \
                *reinterpret_cast<ushort4*>(&xb[idx])   = make_ushort4(xbn[0], xbn[1], xbn[2], xbn[3]); \
            }                                                                  \
        }                                                                      \
        asm volatile("s_waitcnt lgkmcnt(0)" ::: "memory");                     \
    }

// ============================================================================
// KERNEL 1 (fwd/final — R7 winner): deep 4-phase pipeline, 1 blk/CU.
// BM=128, BN=256, 8 waves (2M x 4N), ring-4 BK=32, counted vmcnt.
// ============================================================================
#define PHASE(MB, RB, SLOTP, STTILE, C0, NC)                                   \
    {                                                                          \
        const char* sb_ = (SLOTP);                                             \
        if (RB) {                                                              \
            _Pragma("unroll")                                                  \
            for (int n = 0; n < 4; ++n)                                        \
                bF[n] = *reinterpret_cast<const bf16x8*>(sb_ + bRd[n]);        \
        }                                                                      \
        bf16x8 aF[4];                                                          \
        _Pragma("unroll")                                                      \
        for (int m = 0; m < 4; ++m)                                            \
            aF[m] = *reinterpret_cast<const bf16x8*>(sb_ + aRd[m]);            \
        if ((STTILE) < nt) {                                                   \
            _Pragma("unroll")                                                  \
            for (int c = 0; c < (NC); ++c) stage_chunk((STTILE), (C0) + c);    \
        }                                                                      \
        __builtin_amdgcn_sched_barrier(0);                                     \
        __builtin_amdgcn_s_barrier();                                          \
        asm volatile("s_waitcnt lgkmcnt(0)" ::: "memory");                     \
        __builtin_amdgcn_sched_barrier(0);                                     \
        __builtin_amdgcn_s_setprio(1);                                         \
        _Pragma("unroll")                                                      \
        for (int m = 0; m < 4; ++m) {                                          \
            _Pragma("unroll")                                                  \
            for (int n = 0; n < 4; ++n)                                        \
                acc[m][n] = __builtin_amdgcn_mfma_f32_16x16x32_bf16(           \
                    aF[m], bF[n], acc[m][n], 0, 0, 0);                         \
        }                                                                      \
        __builtin_amdgcn_s_setprio(0);                                         \
        __builtin_amdgcn_s_barrier();                                          \
        __builtin_amdgcn_sched_barrier(0);                                     \
    }

template <int EPI>
__global__ __launch_bounds__(512, 1)
void gemm_phase(const ushortT* __restrict__ A, const ushortT* __restrict__ Bm,
                int N, int K,
                const float* __restrict__ inb, const ushortT* __restrict__ nega,
                ushortT* __restrict__ Gb, float* __restrict__ out,
                ushortT* __restrict__ acc1, ushortT* __restrict__ acc2,
                ushortT* __restrict__ xb) {
    constexpr int BM = 128, BN = 256;
    constexpr int ASZ  = BM * 64;
    constexpr int SLOT = ASZ + BN * 64;
    constexpr int LA   = 1, LB = 2, L = 3;
    __shared__ alignas(16) char smem[4 * SLOT];

    const int tid  = threadIdx.x;
    const int lane = tid & 63;
    const int w    = tid >> 6;
    const int wm   = w >> 2;
    const int wn   = w & 3;
    const int nbx  = N / BN;
    const int nwg  = gridDim.x;
    const int cpx  = nwg >> 3;
    const int bid  = (int)blockIdx.x;
    const int swz  = (bid & 7) * cpx + (bid >> 3);
    const int bx   = swz % nbx;
    const int by   = swz / nbx;
    const int row0 = by * BM;
    const int col0 = bx * BN;
    const size_t strideK2 = (size_t)K * 2;

    const char* gp[L]; int lo[L];
#pragma unroll
    for (int i = 0; i < LA; ++i) {
        int Lp  = i * 512 + tid;
        int row = Lp >> 2, sl = Lp & 3;
        int src = sl ^ ((row >> 1) & 3);
        gp[i] = (const char*)A + (size_t)(row0 + row) * strideK2 + src * 16;
        lo[i] = i * 8192 + w * 1024;
    }
#pragma unroll
    for (int i = 0; i < LB; ++i) {
        int Lp  = i * 512 + tid;
        int row = Lp >> 2, sl = Lp & 3;
        int src = sl ^ ((row >> 1) & 3);
        gp[LA + i] = (const char*)Bm + (size_t)(col0 + row) * strideK2 + src * 16;
        lo[LA + i] = ASZ + i * 8192 + w * 1024;
    }
    auto stage_all = [&](int tt) {
        char* sb = smem + (tt & 3) * SLOT;
        const size_t kb = (size_t)tt * 64;
#pragma unroll
        for (int c = 0; c < L; ++c) gload16(gp[c] + kb, sb + lo[c]);
    };
    auto stage_chunk = [&](int tt, int c) {
        gload16(gp[c] + (size_t)tt * 64, smem + (tt & 3) * SLOT + lo[c]);
    };

    int aRd[4], bRd[4];
#pragma unroll
    for (int m = 0; m < 4; ++m) {
        int row = wm * 64 + m * 16 + (lane & 15);
        aRd[m] = row * 64 + (((lane >> 4) ^ ((row >> 1) & 3)) * 16);
    }
#pragma unroll
    for (int n = 0; n < 4; ++n) {
        int row = wn * 64 + n * 16 + (lane & 15);
        bRd[n] = ASZ + row * 64 + (((lane >> 4) ^ ((row >> 1) & 3)) * 16);
    }

    f32x4 acc[4][4] = {};
    const int nt = K >> 5;

    stage_all(0); stage_all(1); stage_all(2);

    for (int tt = 0; tt < nt; tt += 2) {
        if (tt + 2 < nt) asm volatile("s_waitcnt vmcnt(%0)" :: "n"(L) : "memory");
        else             asm volatile("s_waitcnt vmcnt(0)"  ::: "memory");
        __builtin_amdgcn_s_barrier();
        __builtin_amdgcn_sched_barrier(0);

        const char* sb0 = smem + (tt & 3) * SLOT;
        const char* sb1 = smem + ((tt + 1) & 3) * SLOT;
        bf16x8 bF[4];
        PHASE(0, true, sb0, tt + 3, 0, 3)
        PHASE(0, true, sb1, tt + 4, 0, 3)
    }

    __builtin_amdgcn_s_barrier();
    const int row0w = row0 + wm * 64;
    const int col0w = col0 + wn * 64;
    EPILOGUE(4)
}

// ============================================================================
// KERNEL 2 (grad): 4-wave 256-thread blocks, wave-tile 128x64 (MR=8, NR=4)
// -> LDS reads/MFMA = 0.375 (vs 0.5 at 64x64), the only remaining DS cut.
// BM=256, BN=128, ring-3 (72 KB) -> 2 blk/CU (R8's proven TLP regime).
// Per tile: {vmcnt(6) [0 at tail]; barrier; 12 ds_reads; stage(tt+2);
//            setprio(1); 32 MFMA; setprio(0)}.
// Hazards: RAW -- vmcnt(L)+barrier forces slot tt complete (tt+1 in flight).
//   WAR -- stage(tt+2) -> slot (tt-1)%3 issues after pub(tt) barrier, which
//   follows every wave's slot-(tt-1) reads (lgkmcnt before MFMA, prev iter).
// ============================================================================
template <int EPI>
__global__ __launch_bounds__(256, 2)
void gemm_mb4(const ushortT* __restrict__ A, const ushortT* __restrict__ Bm,
              int N, int K,
              const float* __restrict__ inb, const ushortT* __restrict__ nega,
              ushortT* __restrict__ Gb, float* __restrict__ out,
              ushortT* __restrict__ acc1, ushortT* __restrict__ acc2,
              ushortT* __restrict__ xb) {
    constexpr int BM = 256, BN = 128;
    constexpr int ASZ  = BM * 64;
    constexpr int SLOT = ASZ + BN * 64;      // 24 KB
    constexpr int CA   = 4, CB = 2, L = 6;   // gload chunks per 256-thread tile
    __shared__ alignas(16) char smem[3 * SLOT];

    const int tid  = threadIdx.x;
    const int lane = tid & 63;
    const int w    = tid >> 6;               // 0..3
    const int wm   = w >> 1;                 // 0..1 (M halves of 128)
    const int wn   = w & 1;                  // 0..1 (N halves of 64)
    const int nbx  = N / BN;
    const int nwg  = gridDim.x;
    const int cpx  = nwg >> 3;
    const int bid  = (int)blockIdx.x;
    const int swz  = (bid & 7) * cpx + (bid >> 3);   // XCD-aware bijective
    const int bx   = swz % nbx;
    const int by   = swz / nbx;
    const int row0 = by * BM;
    const int col0 = bx * BN;
    const size_t strideK2 = (size_t)K * 2;

    const char* gp[L]; int lo[L];
#pragma unroll
    for (int c = 0; c < CA; ++c) {
        int Lp  = c * 256 + tid;
        int row = Lp >> 2, sl = Lp & 3;
        int src = sl ^ ((row >> 1) & 3);
        gp[c] = (const char*)A + (size_t)(row0 + row) * strideK2 + src * 16;
        lo[c] = c * 4096 + w * 1024;
    }
#pragma unroll
    for (int c = 0; c < CB; ++c) {
        int Lp  = c * 256 + tid;
        int row = Lp >> 2, sl = Lp & 3;
        int src = sl ^ ((row >> 1) & 3);
        gp[CA + c] = (const char*)Bm + (size_t)(col0 + row) * strideK2 + src * 16;
        lo[CA + c] = ASZ + c * 4096 + w * 1024;
    }
    auto stage = [&](int tt) {
        char* sb = smem + (tt % 3) * SLOT;
        const size_t kb = (size_t)tt * 64;
#pragma unroll
        for (int c = 0; c < L; ++c) gload16(gp[c] + kb, sb + lo[c]);
    };

    int aRd[8], bRd[4];
#pragma unroll
    for (int m = 0; m < 8; ++m) {
        int row = wm * 128 + m * 16 + (lane & 15);
        aRd[m] = row * 64 + (((lane >> 4) ^ ((row >> 1) & 3)) * 16);
    }
#pragma unroll
    for (int n = 0; n < 4; ++n) {
        int row = wn * 64 + n * 16 + (lane & 15);
        bRd[n] = ASZ + row * 64 + (((lane >> 4) ^ ((row >> 1) & 3)) * 16);
    }

    f32x4 acc[8][4] = {};
    const int nt = K >> 5;

    stage(0); stage(1);                      // prologue: 2 tiles in flight

    for (int tt = 0; tt < nt; ++tt) {
        if (tt < nt - 1) asm volatile("s_waitcnt vmcnt(%0)" :: "n"(L) : "memory");
        else             asm volatile("s_waitcnt vmcnt(0)"  ::: "memory");
        __builtin_amdgcn_s_barrier();        // pub(tt)
        __builtin_amdgcn_sched_barrier(0);

        const char* sb = smem + (tt % 3) * SLOT;
        bf16x8 aF[8], bF[4];
#pragma unroll
        for (int n = 0; n < 4; ++n) bF[n] = *reinterpret_cast<const bf16x8*>(sb + bRd[n]);
#pragma unroll
        for (int m = 0; m < 8; ++m) aF[m] = *reinterpret_cast<const bf16x8*>(sb + aRd[m]);
        if (tt + 2 < nt) stage(tt + 2);      // after pub barrier -> WAR-safe
        __builtin_amdgcn_s_setprio(1);
#pragma unroll
        for (int m = 0; m < 8; ++m)
#pragma unroll
            for (int n = 0; n < 4; ++n)
                acc[m][n] = __builtin_amdgcn_mfma_f32_16x16x32_bf16(aF[m], bF[n], acc[m][n], 0, 0, 0);
        __builtin_amdgcn_s_setprio(0);
    }

    __builtin_amdgcn_s_barrier();            // reads retired; reuse LDS
    const int row0w = row0 + wm * 128;
    const int col0w = col0 + wn * 64;
    EPILOGUE(8)
}

extern "C" void kernel_launch(void* const* d_in, const int* in_sizes, int n_in,
                              void* d_out, int out_size, void* d_ws, size_t ws_size,
                              hipStream_t stream) {
    const float* in = (const float*)d_in[0];
    const float* W  = (const float*)d_in[1];
    float* out = (float*)d_out;
    char* ws = (char*)d_ws;

    // workspace layout — 160 MB total
    ushortT* acc1 = (ushortT*)(ws);                            // 32 MB bf16 [4096,4096]
    ushortT* acc2 = (ushortT*)(ws + ((size_t)32  << 20));      // 32 MB bf16
    ushortT* xb   = (ushortT*)(ws + ((size_t)64  << 20));      // 32 MB bf16
    ushortT* Wb   = (ushortT*)(ws + ((size_t)96  << 20));      // 16 MB bf16 [4096,2048]
    ushortT* WTb  = (ushortT*)(ws + ((size_t)112 << 20));      // 16 MB bf16 [2048,4096]
    ushortT* Gb   = (ushortT*)(ws + ((size_t)128 << 20));      // 16 MB bf16 [4096,2048]
    ushortT* negA = (ushortT*)(ws + ((size_t)144 << 20));      // 16 MB bf16 [4096,2048]

    // NO memset: step-0 grad (EPI=3) writes every element of acc1/acc2/xb
    // before anything reads them.

    prep_g0_kernel<<<dim3(B_DIM * IN_DIM / 4 / 256), dim3(256), 0, stream>>>(in, Gb, negA);
    conv_w_kernel<<<dim3(IN_DIM / 64, OUT_DIM / 64), dim3(256), 0, stream>>>(W, Wb, WTb);

    // fwd/final: BM=128,BN=256 -> 32x8  = 256 blocks (deep pipeline, 1 blk/CU)
    // grad:      BM=256,BN=128 -> 16x32 = 512 blocks (4-wave MR=8, 2 blk/CU)
    gemm_mb4<3><<<dim3(512), dim3(256), 0, stream>>>(
        Gb, Wb, OUT_DIM, IN_DIM, nullptr, nullptr, nullptr, nullptr, acc1, acc2, xb);
    for (int step = 1; step < 9; ++step) {
        gemm_phase<0><<<dim3(256), dim3(512), 0, stream>>>(
            xb, WTb, IN_DIM, OUT_DIM, nullptr, negA, Gb, nullptr, nullptr, nullptr, nullptr);
        gemm_mb4<2><<<dim3(512), dim3(256), 0, stream>>>(
            Gb, Wb, OUT_DIM, IN_DIM, nullptr, nullptr, nullptr, nullptr, acc1, acc2, xb);
    }
    gemm_phase<1><<<dim3(256), dim3(512), 0, stream>>>(
        xb, WTb, IN_DIM, OUT_DIM, in, nullptr, nullptr, out, nullptr, nullptr, nullptr);
}

// Round 12
// 1524.552 us; speedup vs baseline: 1.0906x; 1.0073x over previous
//
#include <hip/hip_runtime.h>
#include <cstdint>
#include <cstddef>

#define B_DIM   4096
#define IN_DIM  2048
#define OUT_DIM 4096

typedef __attribute__((ext_vector_type(8))) __bf16 bf16x8;
typedef __attribute__((ext_vector_type(4))) float  f32x4;
typedef unsigned short ushortT;

__device__ __forceinline__ ushortT f2bf(float f) {
    unsigned int u = __float_as_uint(f);
    u += 0x7FFFu + ((u >> 16) & 1u);          // round-to-nearest-even
    return (ushortT)(u >> 16);
}
__device__ __forceinline__ float bf2f(ushortT b) {
    return __uint_as_float(((unsigned int)b) << 16);
}

// global -> LDS direct DMA, 16 B per lane (wave-uniform LDS base, lane i at +i*16).
__device__ __forceinline__ void gload16(const void* g, void* l) {
    __builtin_amdgcn_global_load_lds(
        (const __attribute__((address_space(1))) void*)g,
        (__attribute__((address_space(3))) void*)l, 16, 0, 0);
}

// negA = Gb0 = bf16(-0.05 * sqrt(in^2 + 1e-6))   (step-0 gradient: exp(-0)=1)
__global__ void prep_g0_kernel(const float* __restrict__ in, ushortT* __restrict__ Gb,
                               ushortT* __restrict__ negA) {
    int i = blockIdx.x * 256 + threadIdx.x;
    float4 v = reinterpret_cast<const float4*>(in)[i];
    ushort4 g;
    g.x = f2bf(-0.05f * sqrtf(v.x * v.x + 1e-6f));
    g.y = f2bf(-0.05f * sqrtf(v.y * v.y + 1e-6f));
    g.z = f2bf(-0.05f * sqrtf(v.z * v.z + 1e-6f));
    g.w = f2bf(-0.05f * sqrtf(v.w * v.w + 1e-6f));
    reinterpret_cast<ushort4*>(Gb)[i]   = g;
    reinterpret_cast<ushort4*>(negA)[i] = g;
}

// Wb = bf16(W) [OUT][IN];  WTb = bf16(W^T) [IN][OUT]
__global__ void conv_w_kernel(const float* __restrict__ W, ushortT* __restrict__ Wb,
                              ushortT* __restrict__ WTb) {
    __shared__ float tile[64][65];
    const int i0 = blockIdx.x * 64;
    const int j0 = blockIdx.y * 64;
    const int c  = threadIdx.x & 63;
    const int rq = threadIdx.x >> 6;
#pragma unroll
    for (int rp = 0; rp < 16; ++rp) {
        int row = rp * 4 + rq;
        float w = W[(size_t)(j0 + row) * IN_DIM + i0 + c];
        tile[row][c] = w;
        Wb[(size_t)(j0 + row) * IN_DIM + i0 + c] = f2bf(w);
    }
    __syncthreads();
#pragma unroll
    for (int rp = 0; rp < 16; ++rp) {
        int row = rp * 4 + rq;
        WTb[(size_t)(i0 + row) * OUT_DIM + j0 + c] = f2bf(tile[c][row]);
    }
}

// ---------------------------------------------------------------------------
// Shared epilogue: per-wave LDS re-layout ([16][68] f32) -> coalesced I/O.
// MFMA C layout (m89): acc[m][n][i] -> row (lane>>4)*4+i, col n*16+(lane&15)
//  EPI 0: Gb = bf16(negA * exp(-acc))
//  EPI 1: out = 0.05*(1+exp(-acc))*sqrt(in^2+1e-6)
//  EPI 2: fused RMSProp + prox update of bf16 state xb/acc1/acc2
//  EPI 3: step-0 update (x=a1=a2=0): NO state reads, writes all state
// ---------------------------------------------------------------------------
#define EPILOGUE(MR_)                                                          \
    float* lep = (float*)(smem + w * 4352);                                    \
    const int li = lane >> 4;                                                  \
    const int lc = lane & 15;                                                  \
    _Pragma("unroll")                                                          \
    for (int m = 0; m < (MR_); ++m) {                                          \
        _Pragma("unroll")                                                      \
        for (int n = 0; n < 4; ++n)                                            \
            _Pragma("unroll")                                                  \
            for (int i = 0; i < 4; ++i)                                        \
                lep[(li * 4 + i) * 68 + n * 16 + lc] = acc[m][n][i];           \
        asm volatile("s_waitcnt lgkmcnt(0)" ::: "memory");                     \
        __builtin_amdgcn_sched_barrier(0);                                     \
        _Pragma("unroll")                                                      \
        for (int rr = 0; rr < 4; ++rr) {                                       \
            const int row = rr + li * 4;                                       \
            float4 v = *reinterpret_cast<const float4*>(&lep[row * 68 + lc * 4]); \
            const size_t idx  = (size_t)(row0w + m * 16 + row) * N + col0w + lc * 4; \
            const size_t idx4 = idx >> 2;                                      \
            if constexpr (EPI == 0) {                                          \
                ushort4 au = *reinterpret_cast<const ushort4*>(&nega[idx]);    \
                ushort4 g;                                                     \
                g.x = f2bf(bf2f(au.x) * __expf(-v.x));                         \
                g.y = f2bf(bf2f(au.y) * __expf(-v.y));                         \
                g.z = f2bf(bf2f(au.z) * __expf(-v.z));                         \
                g.w = f2bf(bf2f(au.w) * __expf(-v.w));                         \
                *reinterpret_cast<ushort4*>(&Gb[idx]) = g;                     \
            } else if constexpr (EPI == 1) {                                   \
                float4 iv = reinterpret_cast<const float4*>(inb)[idx4];        \
                float4 o;                                                      \
                o.x = 0.05f * (1.0f + expf(-v.x)) * sqrtf(iv.x * iv.x + 1e-6f); \
                o.y = 0.05f * (1.0f + expf(-v.y)) * sqrtf(iv.y * iv.y + 1e-6f); \
                o.z = 0.05f * (1.0f + expf(-v.z)) * sqrtf(iv.z * iv.z + 1e-6f); \
                o.w = 0.05f * (1.0f + expf(-v.w)) * sqrtf(iv.w * iv.w + 1e-6f); \
                reinterpret_cast<float4*>(out)[idx4] = o;                      \
            } else if constexpr (EPI == 3) {                                   \
                float vs[4] = {v.x, v.y, v.z, v.w};                            \
                ushortT a1n[4], a2n[4], xbn[4];                                \
                _Pragma("unroll")                                              \
                for (int j = 0; j < 4; ++j) {                                  \
                    float g    = vs[j];                                        \
                    float a1   = 0.1f * g * g;                                 \
                    float inv  = rsqrtf(a1 + 1e-8f);                           \
                    float r_   = 0.009f * g * inv;                             \
                    float a2   = -r_;                                          \
                    float cand = -r_;                                          \
                    float t_   = 0.0009f * inv;                                \
                    float xn   = fmaxf(cand - t_, 0.0f) + fminf(cand + t_, 0.0f) + 0.9f * a2; \
                    a1n[j] = f2bf(a1); a2n[j] = f2bf(a2); xbn[j] = f2bf(xn);   \
                }                                                              \
                *reinterpret_cast<ushort4*>(&acc1[idx]) = make_ushort4(a1n[0], a1n[1], a1n[2], a1n[3]); \
                *reinterpret_cast<ushort4*>(&acc2[idx]) = make_ushort4(a2n[0], a2n[1], a2n[2], a2n[3]); \
                *reinterpret_cast<ushort4*>(&xb[idx])   = make_ushort4(xbn[0], xbn[1], xbn[2], xbn[3]); \
            } else {                                                           \
                ushort4 xu  = *reinterpret_cast<const ushort4*>(&xb[idx]);     \
                ushort4 a1u = *reinterpret_cast<const ushort4*>(&acc1[idx]);   \
                ushort4 a2u = *reinterpret_cast<const ushort4*>(&acc2[idx]);   \
                float xs[4] = {bf2f(xu.x), bf2f(xu.y), bf2f(xu.z), bf2f(xu.w)}; \
                float vs[4] = {v.x, v.y, v.z, v.w};                            \
                ushortT a1s[4] = {a1u.x, a1u.y, a1u.z, a1u.w};                 \
                ushortT a2s[4] = {a2u.x, a2u.y, a2u.z, a2u.w};                 \
                ushortT a1n[4], a2n[4], xbn[4];                                \
                _Pragma("unroll")                                              \
                for (int j = 0; j < 4; ++j) {                                  \
                    float g    = vs[j] + 0.02f * xs[j] + 0.1f * xs[j] * rsqrtf(xs[j] * xs[j] + 1e-6f); \
                    float a1   = 0.9f * bf2f(a1s[j]) + 0.1f * g * g;           \
                    float inv  = rsqrtf(a1 + 1e-8f);                           \
                    float r_   = 0.009f * g * inv;                             \
                    float a2   = 0.9f * bf2f(a2s[j]) - r_;                     \
                    float cand = xs[j] - r_;                                   \
                    float t_   = 0.0009f * inv;                                \
                    float xn   = fmaxf(cand - t_, 0.0f) + fminf(cand + t_, 0.0f) + 0.9f * a2; \
                    a1n[j] = f2bf(a1); a2n[j] = f2bf(a2); xbn[j] = f2bf(xn);   \
                }                                                              \
                *reinterpret_cast<ushort4*>(&acc1[idx]) = make_ushort4(a1n[0], a1n[1], a1n[2], a1n[3]); \
                *reinterpret_cast<ushort4*>(&acc2[idx]) = make_ushort4(a2n[0], a2n[1], a2n[2], a2n[3]); \
                *reinterpret_cast<ushort4*>(&xb[idx])   = make_ushort4(xbn[0], xbn[1], xbn[2], xbn[3]); \
            }                                                                  \
        }                                                                      \
        asm volatile("s_waitcnt lgkmcnt(0)" ::: "memory");                     \
    }

// ============================================================================
// KERNEL 1 (fwd/final — R7 winner, measured ~72 us): deep 4-phase pipeline,
// 1 blk/CU. BM=128, BN=256, 8 waves (2M x 4N), ring-4 BK=32, counted vmcnt.
// ============================================================================
#define PHASE(MB, RB, SLOTP, STTILE, C0, NC)                                   \
    {                                                                          \
        const char* sb_ = (SLOTP);                                             \
        if (RB) {                                                              \
            _Pragma("unroll")                                                  \
            for (int n = 0; n < 4; ++n)                                        \
                bF[n] = *reinterpret_cast<const bf16x8*>(sb_ + bRd[n]);        \
        }                                                                      \
        bf16x8 aF[4];                                                          \
        _Pragma("unroll")                                                      \
        for (int m = 0; m < 4; ++m)                                            \
            aF[m] = *reinterpret_cast<const bf16x8*>(sb_ + aRd[m]);            \
        if ((STTILE) < nt) {                                                   \
            _Pragma("unroll")                                                  \
            for (int c = 0; c < (NC); ++c) stage_chunk((STTILE), (C0) + c);    \
        }                                                                      \
        __builtin_amdgcn_sched_barrier(0);                                     \
        __builtin_amdgcn_s_barrier();                                          \
        asm volatile("s_waitcnt lgkmcnt(0)" ::: "memory");                     \
        __builtin_amdgcn_sched_barrier(0);                                     \
        __builtin_amdgcn_s_setprio(1);                                         \
        _Pragma("unroll")                                                      \
        for (int m = 0; m < 4; ++m) {                                          \
            _Pragma("unroll")                                                  \
            for (int n = 0; n < 4; ++n)                                        \
                acc[m][n] = __builtin_amdgcn_mfma_f32_16x16x32_bf16(           \
                    aF[m], bF[n], acc[m][n], 0, 0, 0);                         \
        }                                                                      \
        __builtin_amdgcn_s_setprio(0);                                         \
        __builtin_amdgcn_s_barrier();                                          \
        __builtin_amdgcn_sched_barrier(0);                                     \
    }

template <int EPI>
__global__ __launch_bounds__(512, 1)
void gemm_phase(const ushortT* __restrict__ A, const ushortT* __restrict__ Bm,
                int N, int K,
                const float* __restrict__ inb, const ushortT* __restrict__ nega,
                ushortT* __restrict__ Gb, float* __restrict__ out,
                ushortT* __restrict__ acc1, ushortT* __restrict__ acc2,
                ushortT* __restrict__ xb) {
    constexpr int BM = 128, BN = 256;
    constexpr int ASZ  = BM * 64;
    constexpr int SLOT = ASZ + BN * 64;
    constexpr int LA   = 1, LB = 2, L = 3;
    __shared__ alignas(16) char smem[4 * SLOT];

    const int tid  = threadIdx.x;
    const int lane = tid & 63;
    const int w    = tid >> 6;
    const int wm   = w >> 2;
    const int wn   = w & 3;
    const int nbx  = N / BN;
    const int nwg  = gridDim.x;
    const int cpx  = nwg >> 3;
    const int bid  = (int)blockIdx.x;
    const int swz  = (bid & 7) * cpx + (bid >> 3);
    const int bx   = swz % nbx;
    const int by   = swz / nbx;
    const int row0 = by * BM;
    const int col0 = bx * BN;
    const size_t strideK2 = (size_t)K * 2;

    const char* gp[L]; int lo[L];
#pragma unroll
    for (int i = 0; i < LA; ++i) {
        int Lp  = i * 512 + tid;
        int row = Lp >> 2, sl = Lp & 3;
        int src = sl ^ ((row >> 1) & 3);
        gp[i] = (const char*)A + (size_t)(row0 + row) * strideK2 + src * 16;
        lo[i] = i * 8192 + w * 1024;
    }
#pragma unroll
    for (int i = 0; i < LB; ++i) {
        int Lp  = i * 512 + tid;
        int row = Lp >> 2, sl = Lp & 3;
        int src = sl ^ ((row >> 1) & 3);
        gp[LA + i] = (const char*)Bm + (size_t)(col0 + row) * strideK2 + src * 16;
        lo[LA + i] = ASZ + i * 8192 + w * 1024;
    }
    auto stage_all = [&](int tt) {
        char* sb = smem + (tt & 3) * SLOT;
        const size_t kb = (size_t)tt * 64;
#pragma unroll
        for (int c = 0; c < L; ++c) gload16(gp[c] + kb, sb + lo[c]);
    };
    auto stage_chunk = [&](int tt, int c) {
        gload16(gp[c] + (size_t)tt * 64, smem + (tt & 3) * SLOT + lo[c]);
    };

    int aRd[4], bRd[4];
#pragma unroll
    for (int m = 0; m < 4; ++m) {
        int row = wm * 64 + m * 16 + (lane & 15);
        aRd[m] = row * 64 + (((lane >> 4) ^ ((row >> 1) & 3)) * 16);
    }
#pragma unroll
    for (int n = 0; n < 4; ++n) {
        int row = wn * 64 + n * 16 + (lane & 15);
        bRd[n] = ASZ + row * 64 + (((lane >> 4) ^ ((row >> 1) & 3)) * 16);
    }

    f32x4 acc[4][4] = {};
    const int nt = K >> 5;

    stage_all(0); stage_all(1); stage_all(2);

    for (int tt = 0; tt < nt; tt += 2) {
        if (tt + 2 < nt) asm volatile("s_waitcnt vmcnt(%0)" :: "n"(L) : "memory");
        else             asm volatile("s_waitcnt vmcnt(0)"  ::: "memory");
        __builtin_amdgcn_s_barrier();
        __builtin_amdgcn_sched_barrier(0);

        const char* sb0 = smem + (tt & 3) * SLOT;
        const char* sb1 = smem + ((tt + 1) & 3) * SLOT;
        bf16x8 bF[4];
        PHASE(0, true, sb0, tt + 3, 0, 3)
        PHASE(0, true, sb1, tt + 4, 0, 3)
    }

    __builtin_amdgcn_s_barrier();
    const int row0w = row0 + wm * 64;
    const int col0w = col0 + wn * 64;
    EPILOGUE(4)
}

// ============================================================================
// KERNEL 2 (grad — R8/R10 winner, measured 94.6 us): ring-3, counted vmcnt(3),
// 72 KB -> 2 blk/CU, 16 waves/CU. BM=256, BN=128, 8 waves (4M x 2N).
// Per tile: {vmcnt(L) [0 at tail]; barrier; 8 ds_reads; stage(tt+2);
//            setprio(1); 16 MFMA; setprio(0)}.
// Hazards: RAW -- vmcnt(L)+barrier forces slot tt complete (tt+1 in flight).
//   WAR -- stage(tt+2) -> slot (tt-1)%3 issues after pub(tt) barrier, which
//   follows every wave's slot-(tt-1) reads (lgkmcnt before MFMA, prev iter).
// ============================================================================
template <int EPI>
__global__ __launch_bounds__(512, 4)
void gemm_mb(const ushortT* __restrict__ A, const ushortT* __restrict__ Bm,
             int N, int K,
             const float* __restrict__ inb, const ushortT* __restrict__ nega,
             ushortT* __restrict__ Gb, float* __restrict__ out,
             ushortT* __restrict__ acc1, ushortT* __restrict__ acc2,
             ushortT* __restrict__ xb) {
    constexpr int BM = 256, BN = 128;
    constexpr int ASZ  = BM * 64;
    constexpr int SLOT = ASZ + BN * 64;      // 24 KB
    constexpr int CA   = 2, CB = 1, L = 3;
    __shared__ alignas(16) char smem[3 * SLOT];

    const int tid  = threadIdx.x;
    const int lane = tid & 63;
    const int w    = tid >> 6;
    const int wm   = w >> 1;                 // 0..3 (M)
    const int wn   = w & 1;                  // 0..1 (N)
    const int nbx  = N / BN;
    const int nwg  = gridDim.x;
    const int cpx  = nwg >> 3;
    const int bid  = (int)blockIdx.x;
    const int swz  = (bid & 7) * cpx + (bid >> 3);
    const int bx   = swz % nbx;
    const int by   = swz / nbx;
    const int row0 = by * BM;
    const int col0 = bx * BN;
    const size_t strideK2 = (size_t)K * 2;

    const char* gp[L]; int lo[L];
#pragma unroll
    for (int c = 0; c < CA; ++c) {
        int Lp  = c * 512 + tid;
        int row = Lp >> 2, sl = Lp & 3;
        int src = sl ^ ((row >> 1) & 3);
        gp[c] = (const char*)A + (size_t)(row0 + row) * strideK2 + src * 16;
        lo[c] = c * 8192 + w * 1024;
    }
#pragma unroll
    for (int c = 0; c < CB; ++c) {
        int Lp  = c * 512 + tid;
        int row = Lp >> 2, sl = Lp & 3;
        int src = sl ^ ((row >> 1) & 3);
        gp[CA + c] = (const char*)Bm + (size_t)(col0 + row) * strideK2 + src * 16;
        lo[CA + c] = ASZ + c * 8192 + w * 1024;
    }
    auto stage = [&](int tt) {
        char* sb = smem + (tt % 3) * SLOT;
        const size_t kb = (size_t)tt * 64;
#pragma unroll
        for (int c = 0; c < L; ++c) gload16(gp[c] + kb, sb + lo[c]);
    };

    int aRd[4], bRd[4];
#pragma unroll
    for (int m = 0; m < 4; ++m) {
        int row = wm * 64 + m * 16 + (lane & 15);
        aRd[m] = row * 64 + (((lane >> 4) ^ ((row >> 1) & 3)) * 16);
    }
#pragma unroll
    for (int n = 0; n < 4; ++n) {
        int row = wn * 64 + n * 16 + (lane & 15);
        bRd[n] = ASZ + row * 64 + (((lane >> 4) ^ ((row >> 1) & 3)) * 16);
    }

    f32x4 acc[4][4] = {};
    const int nt = K >> 5;

    stage(0); stage(1);                      // prologue: 2 tiles in flight

    for (int tt = 0; tt < nt; ++tt) {
        if (tt < nt - 1) asm volatile("s_waitcnt vmcnt(%0)" :: "n"(L) : "memory");
        else             asm volatile("s_waitcnt vmcnt(0)"  ::: "memory");
        __builtin_amdgcn_s_barrier();        // pub(tt)
        __builtin_amdgcn_sched_barrier(0);

        const char* sb = smem + (tt % 3) * SLOT;
        bf16x8 aF[4], bF[4];
#pragma unroll
        for (int n = 0; n < 4; ++n) bF[n] = *reinterpret_cast<const bf16x8*>(sb + bRd[n]);
#pragma unroll
        for (int m = 0; m < 4; ++m) aF[m] = *reinterpret_cast<const bf16x8*>(sb + aRd[m]);
        if (tt + 2 < nt) stage(tt + 2);      // after pub barrier -> WAR-safe
        __builtin_amdgcn_s_setprio(1);
#pragma unroll
        for (int m = 0; m < 4; ++m)
#pragma unroll
            for (int n = 0; n < 4; ++n)
                acc[m][n] = __builtin_amdgcn_mfma_f32_16x16x32_bf16(aF[m], bF[n], acc[m][n], 0, 0, 0);
        __builtin_amdgcn_s_setprio(0);
    }

    __builtin_amdgcn_s_barrier();            // reads retired; reuse LDS
    const int row0w = row0 + wm * 64;
    const int col0w = col0 + wn * 64;
    EPILOGUE(4)
}

extern "C" void kernel_launch(void* const* d_in, const int* in_sizes, int n_in,
                              void* d_out, int out_size, void* d_ws, size_t ws_size,
                              hipStream_t stream) {
    const float* in = (const float*)d_in[0];
    const float* W  = (const float*)d_in[1];
    float* out = (float*)d_out;
    char* ws = (char*)d_ws;

    // workspace layout — 160 MB total
    ushortT* acc1 = (ushortT*)(ws);                            // 32 MB bf16 [4096,4096]
    ushortT* acc2 = (ushortT*)(ws + ((size_t)32  << 20));      // 32 MB bf16
    ushortT* xb   = (ushortT*)(ws + ((size_t)64  << 20));      // 32 MB bf16
    ushortT* Wb   = (ushortT*)(ws + ((size_t)96  << 20));      // 16 MB bf16 [4096,2048]
    ushortT* WTb  = (ushortT*)(ws + ((size_t)112 << 20));      // 16 MB bf16 [2048,4096]
    ushortT* Gb   = (ushortT*)(ws + ((size_t)128 << 20));      // 16 MB bf16 [4096,2048]
    ushortT* negA = (ushortT*)(ws + ((size_t)144 << 20));      // 16 MB bf16 [4096,2048]

    // NO memset: step-0 grad (EPI=3) writes every element of acc1/acc2/xb
    // before anything reads them.

    prep_g0_kernel<<<dim3(B_DIM * IN_DIM / 4 / 256), dim3(256), 0, stream>>>(in, Gb, negA);
    conv_w_kernel<<<dim3(IN_DIM / 64, OUT_DIM / 64), dim3(256), 0, stream>>>(W, Wb, WTb);

    // fwd/final: BM=128,BN=256 -> 32x8  = 256 blocks (deep pipeline, 1 blk/CU)
    // grad:      BM=256,BN=128 -> 16x32 = 512 blocks (8-wave ring-3, 2 blk/CU)
    gemm_mb<3><<<dim3(512), dim3(512), 0, stream>>>(
        Gb, Wb, OUT_DIM, IN_DIM, nullptr, nullptr, nullptr, nullptr, acc1, acc2, xb);
    for (int step = 1; step < 9; ++step) {
        gemm_phase<0><<<dim3(256), dim3(512), 0, stream>>>(
            xb, WTb, IN_DIM, OUT_DIM, nullptr, negA, Gb, nullptr, nullptr, nullptr, nullptr);
        gemm_mb<2><<<dim3(512), dim3(512), 0, stream>>>(
            Gb, Wb, OUT_DIM, IN_DIM, nullptr, nullptr, nullptr, nullptr, acc1, acc2, xb);
    }
    gemm_phase<1><<<dim3(256), dim3(512), 0, stream>>>(
        xb, WTb, IN_DIM, OUT_DIM, in, nullptr, nullptr, out, nullptr, nullptr, nullptr);
}